// Round 10
// baseline (154.271 us; speedup 1.0000x reference)
//
#include <hip/hip_runtime.h>
#include <math.h>

// B=4, T=2048, N_EMBD=1024, HEAD=64.
// Reference multiplies scores by sqrt(64)=8; we fold 8*log2(e) into q and use exp2.
#define NE 1024
#define HS 64
#define TT 2048
#define QSC 11.541560327111707f   // 8 * log2(e)

typedef __bf16    v8bf __attribute__((ext_vector_type(8)));
typedef _Float16  v8h  __attribute__((ext_vector_type(8)));
typedef float     v4f  __attribute__((ext_vector_type(4)));

#define MFMA_BF(a, b, c)  __builtin_amdgcn_mfma_f32_16x16x32_bf16((a), (b), (c), 0, 0, 0)
#define MFMA_F16(a, b, c) __builtin_amdgcn_mfma_f32_16x16x32_f16((a), (b), (c), 0, 0, 0)

// async global->LDS DMA (lands at wave-uniform base + lane*size)
__device__ __forceinline__ void gl_lds16(const void* g, void* l) {
    __builtin_amdgcn_global_load_lds(
        (const __attribute__((address_space(1))) unsigned int*)g,
        (__attribute__((address_space(3))) unsigned int*)l, 16, 0, 0);
}

// raw barrier with manual vmcnt: NO compiler-inserted vmcnt(0) drain.
#define SYNC_VM(imm) do {                                   \
    __asm__ __volatile__("" ::: "memory");                  \
    __builtin_amdgcn_s_waitcnt(imm);                        \
    __builtin_amdgcn_s_barrier();                           \
    __asm__ __volatile__("" ::: "memory");                  \
} while (0)
#define WAIT_VM4  0x0F74   // vmcnt(4)
#define WAIT_VM0  0x0F70   // vmcnt(0)

// ---------------------------------------------------------------------------
// prep_w: unchanged.
// ---------------------------------------------------------------------------
__global__ __launch_bounds__(256) void prep_w(
    const float* __restrict__ Wq, const float* __restrict__ Wk,
    const float* __restrict__ Wv, char* __restrict__ imgW)
{
    __shared__ float t[64][65];
    const int bx = blockIdx.x, by = blockIdx.y;
    const float* W = (by == 0) ? Wq : ((by == 1) ? Wk : Wv);
    const int tid = threadIdx.x;
    const int cc = tid & 63, r4 = tid >> 6;
    #pragma unroll
    for (int p = 0; p < 16; ++p) {
        const int k = p * 4 + r4;
        t[k][cc] = W[(size_t)(bx * 64 + k) * HS + cc];   // coalesced
    }
    __syncthreads();
    #pragma unroll
    for (int e = 0; e < 4; ++e) {
        const int chunk = tid + e * 256;
        const int s2   = chunk >> 9;
        const int rem  = chunk & 511;
        const int ctl  = rem >> 7;
        const int rem2 = rem & 127;
        const int pl   = rem2 >> 6;
        const int rem3 = rem2 & 63;
        const int c    = rem3 >> 2;
        const int p16  = rem3 & 3;
        const int kb   = s2 * 32 + ((p16 ^ (c & 3)) << 3);
        const int ncol = ctl * 16 + c;
        v8bf o;
        #pragma unroll
        for (int j = 0; j < 8; ++j) {
            const float v = t[kb + j][ncol];
            const __bf16 h = (__bf16)v;
            o[j] = pl ? (__bf16)(v - (float)h) : h;
        }
        *(v8bf*)(imgW + (size_t)(bx * 2 + s2) * 24576
                 + (by * 4 + ctl) * 2048 + pl * 1024 + c * 64 + p16 * 16) = o;
    }
}

// ---------------------------------------------------------------------------
// Projection GEMM v2 (unchanged): 512 blocks x 256 thr, 32x96 tile.
// ---------------------------------------------------------------------------
__global__ __launch_bounds__(256, 2) void proj(
    const float* __restrict__ x, const char* __restrict__ imgW,
    const float* __restrict__ bq, const float* __restrict__ bk,
    const float* __restrict__ bv,
    _Float16* __restrict__ qh, _Float16* __restrict__ ql,
    _Float16* __restrict__ kf, _Float16* __restrict__ vt)
{
    __shared__ __align__(16) char sbuf[3][16384];   // [buf][x 4KB | W 12KB]

    const int tid = threadIdx.x, lane = tid & 63, cg = tid >> 6;
    const int quad = lane >> 4, l16 = lane & 15;
    const int bx = blockIdx.x;
    const int m0 = (bx >> 1) * 32;          // 32-row tile
    const int h  = bx & 1;                  // col half

    const int xrow = cg * 8 + (lane >> 3);
    const int xp   = (lane >> 1) & 3;
    const int xh   = lane & 1;
    const float* gx = x + (size_t)(m0 + xrow) * NE
                        + ((xp ^ (xrow & 3)) << 3) + (xh << 2);
    const int xl = cg * 1024 + lane * 16;
    const char* gw = imgW + (size_t)h * 12288 + (size_t)tid * 16;

    v4f acc[3];
    #pragma unroll
    for (int i = 0; i < 3; ++i) acc[i] = (v4f){0.f, 0.f, 0.f, 0.f};

    #define STAGE(ks, xb_)  do {                                          \
        gl_lds16(gx + (ks) * 32, (xb_) + xl);                             \
        const char* gws_ = gw + (size_t)(ks) * 24576;                     \
        _Pragma("unroll")                                                 \
        for (int j_ = 0; j_ < 3; ++j_)                                    \
            gl_lds16(gws_ + j_ * 4096, (xb_) + 4096 + tid * 16 + j_ * 4096); \
    } while (0)

    auto compute = [&](int ks) {
        const char* xb = sbuf[ks % 3];
        const char* wb = xb + 4096;
        const int mt = cg >> 1;
        const int wc = cg & 1;
        const int rl = mt * 16 + l16;
        const int pA = quad ^ (rl & 3);
        const float4 a0 = *(const float4*)(xb + rl * 128 + pA * 32);
        const float4 a1 = *(const float4*)(xb + rl * 128 + pA * 32 + 16);
        const float av[8] = {a0.x, a0.y, a0.z, a0.w, a1.x, a1.y, a1.z, a1.w};
        v8bf ah, al;
        #pragma unroll
        for (int i = 0; i < 8; ++i) {
            const __bf16 hv = (__bf16)av[i];
            ah[i] = hv;
            al[i] = (__bf16)(av[i] - (float)hv);
        }
        const int wo = l16 * 64 + ((quad ^ (l16 & 3)) << 4);
        #pragma unroll
        for (int j = 0; j < 3; ++j) {
            const char* base = wb + (wc * 3 + j) * 2048 + wo;
            const v8bf bh = *(const v8bf*)(base);
            const v8bf bl = *(const v8bf*)(base + 1024);
            acc[j] = MFMA_BF(ah, bh, acc[j]);
            acc[j] = MFMA_BF(ah, bl, acc[j]);
            acc[j] = MFMA_BF(al, bh, acc[j]);
        }
    };

    STAGE(0, sbuf[0]);
    STAGE(1, sbuf[1]);
    for (int ks = 0; ks < 31; ++ks) {
        SYNC_VM(WAIT_VM4);
        if (ks + 2 < 32) STAGE(ks + 2, sbuf[(ks + 2) % 3]);
        compute(ks);
    }
    SYNC_VM(WAIT_VM0);
    compute(31);
    #undef STAGE

    const int mt = cg >> 1, wc = cg & 1;
    #pragma unroll
    for (int j = 0; j < 3; ++j) {
        const int n = h * 96 + wc * 48 + j * 16 + l16;
        const float bias = (n < 64) ? bq[n] : ((n < 128) ? bk[n - 64] : bv[n - 128]);
        #pragma unroll
        for (int reg = 0; reg < 4; ++reg) {
            const int row = m0 + mt * 16 + quad * 4 + reg;
            const float v = acc[j][reg] + bias;
            if (n < 64) {
                const float s = v * QSC;
                const _Float16 hh = (_Float16)s;
                qh[(size_t)row * HS + n] = hh;
                ql[(size_t)row * HS + n] = (_Float16)(s - (float)hh);
            } else if (n < 128) {
                kf[(size_t)row * HS + n - 64] = (_Float16)v;
            } else {
                const int b2 = row >> 11, tt = row & 2047, hc = n - 128;
                vt[((size_t)(b2 * HS + hc)) * TT + tt] = (_Float16)v;
            }
        }
    }
}

// ---------------------------------------------------------------------------
// Flash attention v5 = v4 minus the register cap. Measured (r9): with
// __launch_bounds__(1024,4) the allocator was squeezed to VGPR=64 and spilled
// (WRITE_SIZE 65MB of scratch vs 2MB of out; attn 48.6µs; total 153.7).
// Occupancy DID rise to ~40% — the TLP mechanism works; spills ate it.
// A 1024-thread workgroup already forces 16 waves co-resident (4 waves/SIMD)
// so the HW cap of 128 VGPR applies automatically; the v2 body needs ~104.
// Fix: __launch_bounds__(1024) with no min-occupancy arg. Nothing else changed.
// ---------------------------------------------------------------------------
__global__ __launch_bounds__(1024) void attn(
    const _Float16* __restrict__ qh, const _Float16* __restrict__ ql,
    const _Float16* __restrict__ kf, const _Float16* __restrict__ vt,
    float* __restrict__ out)
{
    __shared__ __align__(16) char smem_raw[69632];   // P bufs (36.9KB) / os merge (69.6KB), time-shared
    _Float16* ps = (_Float16*)smem_raw;
    float*    os = (float*)smem_raw;
    __shared__ float sm[16][2][16], sl[16][2][16];

    const int tid = threadIdx.x, lane = tid & 63, w = tid >> 6;   // w 0..15
    const int quad = lane >> 4, l16 = lane & 15;
    const int b = blockIdx.x & 3, pair = blockIdx.x >> 2;         // pair 0..63
    const int q0t[2] = {(127 - pair) * 16, pair * 16};
    const int ntk0 = (q0t[0] + 16 + 63) >> 6;
    const int ntk1 = (q0t[1] + 16 + 63) >> 6;
    const int total = ntk0 + ntk1;                                // == 33

    v8h Qh0[2], Qh1[2], Ql0[2], Ql1[2];
    #pragma unroll
    for (int t = 0; t < 2; ++t) {
        const size_t qrow = ((size_t)b * TT + q0t[t] + l16) * HS;
        Qh0[t] = *(const v8h*)(qh + qrow + quad * 8);
        Qh1[t] = *(const v8h*)(qh + qrow + 32 + quad * 8);
        Ql0[t] = *(const v8h*)(ql + qrow + quad * 8);
        Ql1[t] = *(const v8h*)(ql + qrow + 32 + quad * 8);
    }

    const v8h vones = {(_Float16)1.f, (_Float16)1.f, (_Float16)1.f, (_Float16)1.f,
                       (_Float16)1.f, (_Float16)1.f, (_Float16)1.f, (_Float16)1.f};

    float mr0[4] = {-3e38f, -3e38f, -3e38f, -3e38f};
    float mr1[4] = {-3e38f, -3e38f, -3e38f, -3e38f};
    v4f o0[4], o1[4], l40, l41;
    #pragma unroll
    for (int i = 0; i < 4; ++i) {
        o0[i] = (v4f){0.f, 0.f, 0.f, 0.f};
        o1[i] = (v4f){0.f, 0.f, 0.f, 0.f};
    }
    l40 = (v4f){0.f, 0.f, 0.f, 0.f};
    l41 = (v4f){0.f, 0.f, 0.f, 0.f};

    _Float16* pw = ps + w * (16 * 72);     // 16 waves x 2304 B = 36864 B

    auto doChunk = [&](int j0, int q0c, int t,
                       float (&mrow)[4], v4f (&o)[4], v4f &o4) {
        v8h Kf[8], Vf[8];
        #pragma unroll
        for (int nt = 0; nt < 4; ++nt) {
            const size_t krow = ((size_t)b * TT + j0 + nt * 16 + l16) * HS;
            Kf[nt * 2]     = *(const v8h*)(kf + krow + quad * 8);
            Kf[nt * 2 + 1] = *(const v8h*)(kf + krow + 32 + quad * 8);
        }
        #pragma unroll
        for (int nt = 0; nt < 4; ++nt) {
            const size_t vrow = ((size_t)(b * HS + nt * 16 + l16)) * TT + j0;
            Vf[nt * 2]     = *(const v8h*)(vt + vrow + quad * 8);
            Vf[nt * 2 + 1] = *(const v8h*)(vt + vrow + 32 + quad * 8);
        }
        v4f s[4];
        #pragma unroll
        for (int i = 0; i < 4; ++i) s[i] = (v4f){0.f, 0.f, 0.f, 0.f};
        #pragma unroll
        for (int nt = 0; nt < 4; ++nt) {
            s[nt] = MFMA_F16(Qh0[t], Kf[nt * 2],     s[nt]);
            s[nt] = MFMA_F16(Qh1[t], Kf[nt * 2 + 1], s[nt]);
            s[nt] = MFMA_F16(Ql0[t], Kf[nt * 2],     s[nt]);
            s[nt] = MFMA_F16(Ql1[t], Kf[nt * 2 + 1], s[nt]);
        }
        const int irow = q0c + quad * 4;
        float mx[4] = {-3e38f, -3e38f, -3e38f, -3e38f};
        #pragma unroll
        for (int nt = 0; nt < 4; ++nt)
            #pragma unroll
            for (int reg = 0; reg < 4; ++reg) {
                if (j0 + nt * 16 + l16 > irow + reg) s[nt][reg] = -3e38f;
                mx[reg] = fmaxf(mx[reg], s[nt][reg]);
            }
        #pragma unroll
        for (int off = 8; off; off >>= 1)
            #pragma unroll
            for (int reg = 0; reg < 4; ++reg)
                mx[reg] = fmaxf(mx[reg], __shfl_xor(mx[reg], off));
        float al[4];
        #pragma unroll
        for (int reg = 0; reg < 4; ++reg) {
            const float mn = fmaxf(mrow[reg], mx[reg]);
            al[reg] = exp2f(mrow[reg] - mn);
            mrow[reg] = mn;
        }
        #pragma unroll
        for (int nt = 0; nt < 4; ++nt)
            #pragma unroll
            for (int reg = 0; reg < 4; ++reg) {
                const float p = (j0 + nt * 16 + l16 > irow + reg)
                                    ? 0.f : exp2f(s[nt][reg] - mrow[reg]);
                pw[(quad * 4 + reg) * 72 + nt * 16 + l16] = (_Float16)p;
            }
        #pragma unroll
        for (int nt = 0; nt < 4; ++nt)
            #pragma unroll
            for (int reg = 0; reg < 4; ++reg)
                o[nt][reg] *= al[reg];
        #pragma unroll
        for (int reg = 0; reg < 4; ++reg)
            o4[reg] *= al[reg];
        const v8h Pa0 = *(const v8h*)(pw + l16 * 72 + quad * 8);
        const v8h Pa1 = *(const v8h*)(pw + l16 * 72 + 32 + quad * 8);
        #pragma unroll
        for (int nt = 0; nt < 4; ++nt) {
            o[nt] = MFMA_F16(Pa0, Vf[nt * 2],     o[nt]);
            o[nt] = MFMA_F16(Pa1, Vf[nt * 2 + 1], o[nt]);
        }
        o4 = MFMA_F16(Pa0, vones, o4);
        o4 = MFMA_F16(Pa1, vones, o4);
    };

    for (int c = w; c < total; c += 16) {
        if (c < ntk0) doChunk(c * 64,          q0t[0], 0, mr0, o0, l40);
        else          doChunk((c - ntk0) * 64, q0t[1], 1, mr1, o1, l41);
    }

    if (l16 == 0) {
        #pragma unroll
        for (int reg = 0; reg < 4; ++reg) {
            sm[w][0][quad * 4 + reg] = mr0[reg];
            sl[w][0][quad * 4 + reg] = l40[reg];
            sm[w][1][quad * 4 + reg] = mr1[reg];
            sl[w][1][quad * 4 + reg] = l41[reg];
        }
    }
    __syncthreads();

    // --- two-pass exact merge: pass p has waves p*8..p*8+7 write os, then
    // all threads accumulate their 8 slots. Same global M everywhere. ---
    float val2[2] = {0.f, 0.f};
    #pragma unroll
    for (int pass = 0; pass < 2; ++pass) {
        if ((w >> 3) == pass) {
            #pragma unroll
            for (int t = 0; t < 2; ++t) {
                float sc[4];
                #pragma unroll
                for (int reg = 0; reg < 4; ++reg) {
                    const int r = quad * 4 + reg;
                    float M = sm[0][t][r];
                    #pragma unroll
                    for (int i = 1; i < 16; ++i) M = fmaxf(M, sm[i][t][r]);
                    const float mw = t ? mr1[reg] : mr0[reg];
                    sc[reg] = exp2f(mw - M);
                }
                float* ow = os + (size_t)((w & 7) * 2 + t) * (16 * 68);
                #pragma unroll
                for (int nt = 0; nt < 4; ++nt)
                    #pragma unroll
                    for (int reg = 0; reg < 4; ++reg) {
                        const v4f& oo = t ? o1[nt] : o0[nt];
                        ow[(quad * 4 + reg) * 68 + nt * 16 + l16] = oo[reg] * sc[reg];
                    }
            }
        }
        __syncthreads();
        {
            const int t = w >> 3;
            #pragma unroll
            for (int kk = 0; kk < 2; ++kk) {
                const int m = (w * 2 + kk) & 15;
                #pragma unroll
                for (int i = 0; i < 8; ++i)
                    val2[kk] += os[(size_t)(i * 2 + t) * (16 * 68) + m * 68 + lane];
            }
        }
        __syncthreads();   // reads done before next pass overwrites
    }

    {
        const int t = w >> 3;
        #pragma unroll
        for (int kk = 0; kk < 2; ++kk) {
            const int m = (w * 2 + kk) & 15;
            float M = sm[0][t][m];
            #pragma unroll
            for (int i = 1; i < 16; ++i) M = fmaxf(M, sm[i][t][m]);
            float L = 0.f;
            #pragma unroll
            for (int i = 0; i < 16; ++i)
                L += sl[i][t][m] * exp2f(sm[i][t][m] - M);
            out[((size_t)b * TT + q0t[t] + m) * HS + lane] = val2[kk] / L;
        }
    }
}

// ---------------------------------------------------------------------------
extern "C" void kernel_launch(void* const* d_in, const int* in_sizes, int n_in,
                              void* d_out, int out_size, void* d_ws, size_t ws_size,
                              hipStream_t stream)
{
    const float* x  = (const float*)d_in[0];
    const float* Wq = (const float*)d_in[1];
    const float* bq = (const float*)d_in[2];
    const float* Wk = (const float*)d_in[3];
    const float* bk = (const float*)d_in[4];
    const float* Wv = (const float*)d_in[5];
    const float* bv = (const float*)d_in[6];
    float* out = (float*)d_out;

    const int rows = in_sizes[0] / NE;   // 8192
    char* p = (char*)d_ws;
    char* imgW = p;                           p += (size_t)32 * 24576;      // 768 KB
    _Float16* qhb = (_Float16*)p;             p += (size_t)rows * HS * 2;
    _Float16* qlb = (_Float16*)p;             p += (size_t)rows * HS * 2;
    _Float16* kfb = (_Float16*)p;             p += (size_t)rows * HS * 2;
    _Float16* vtb = (_Float16*)p;             p += (size_t)rows * HS * 2;

    prep_w<<<dim3(16, 3), 256, 0, stream>>>(Wq, Wk, Wv, imgW);
    proj<<<rows / 16, 256, 0, stream>>>(x, imgW, bq, bk, bv,
                                        qhb, qlb, kfb, vtb);
    attn<<<rows / 32, 1024, 0, stream>>>(qhb, qlb, kfb, vtb, out);
}

// Round 11
// 150.535 us; speedup vs baseline: 1.0248x; 1.0248x over previous
//
#include <hip/hip_runtime.h>
#include <math.h>

// B=4, T=2048, N_EMBD=1024, HEAD=64.
// Reference multiplies scores by sqrt(64)=8; we fold 8*log2(e) into q and use exp2.
#define NE 1024
#define HS 64
#define TT 2048
#define QSC 11.541560327111707f   // 8 * log2(e)

typedef __bf16    v8bf __attribute__((ext_vector_type(8)));
typedef _Float16  v8h  __attribute__((ext_vector_type(8)));
typedef float     v4f  __attribute__((ext_vector_type(4)));

#define MFMA_BF(a, b, c)  __builtin_amdgcn_mfma_f32_16x16x32_bf16((a), (b), (c), 0, 0, 0)
#define MFMA_F16(a, b, c) __builtin_amdgcn_mfma_f32_16x16x32_f16((a), (b), (c), 0, 0, 0)

// async global->LDS DMA (lands at wave-uniform base + lane*size)
__device__ __forceinline__ void gl_lds16(const void* g, void* l) {
    __builtin_amdgcn_global_load_lds(
        (const __attribute__((address_space(1))) unsigned int*)g,
        (__attribute__((address_space(3))) unsigned int*)l, 16, 0, 0);
}

// raw barrier with manual vmcnt: NO compiler-inserted vmcnt(0) drain.
#define SYNC_VM(imm) do {                                   \
    __asm__ __volatile__("" ::: "memory");                  \
    __builtin_amdgcn_s_waitcnt(imm);                        \
    __builtin_amdgcn_s_barrier();                           \
    __asm__ __volatile__("" ::: "memory");                  \
} while (0)
#define WAIT_VM4  0x0F74   // vmcnt(4)
#define WAIT_VM0  0x0F70   // vmcnt(0)

// ---------------------------------------------------------------------------
// prep_w: unchanged.
// ---------------------------------------------------------------------------
__global__ __launch_bounds__(256) void prep_w(
    const float* __restrict__ Wq, const float* __restrict__ Wk,
    const float* __restrict__ Wv, char* __restrict__ imgW)
{
    __shared__ float t[64][65];
    const int bx = blockIdx.x, by = blockIdx.y;
    const float* W = (by == 0) ? Wq : ((by == 1) ? Wk : Wv);
    const int tid = threadIdx.x;
    const int cc = tid & 63, r4 = tid >> 6;
    #pragma unroll
    for (int p = 0; p < 16; ++p) {
        const int k = p * 4 + r4;
        t[k][cc] = W[(size_t)(bx * 64 + k) * HS + cc];   // coalesced
    }
    __syncthreads();
    #pragma unroll
    for (int e = 0; e < 4; ++e) {
        const int chunk = tid + e * 256;
        const int s2   = chunk >> 9;
        const int rem  = chunk & 511;
        const int ctl  = rem >> 7;
        const int rem2 = rem & 127;
        const int pl   = rem2 >> 6;
        const int rem3 = rem2 & 63;
        const int c    = rem3 >> 2;
        const int p16  = rem3 & 3;
        const int kb   = s2 * 32 + ((p16 ^ (c & 3)) << 3);
        const int ncol = ctl * 16 + c;
        v8bf o;
        #pragma unroll
        for (int j = 0; j < 8; ++j) {
            const float v = t[kb + j][ncol];
            const __bf16 h = (__bf16)v;
            o[j] = pl ? (__bf16)(v - (float)h) : h;
        }
        *(v8bf*)(imgW + (size_t)(bx * 2 + s2) * 24576
                 + (by * 4 + ctl) * 2048 + pl * 1024 + c * 64 + p16 * 16) = o;
    }
}

// ---------------------------------------------------------------------------
// Projection GEMM v2 (unchanged): 512 blocks x 256 thr, 32x96 tile.
// ---------------------------------------------------------------------------
__global__ __launch_bounds__(256, 2) void proj(
    const float* __restrict__ x, const char* __restrict__ imgW,
    const float* __restrict__ bq, const float* __restrict__ bk,
    const float* __restrict__ bv,
    _Float16* __restrict__ qh, _Float16* __restrict__ ql,
    _Float16* __restrict__ kf, _Float16* __restrict__ vt)
{
    __shared__ __align__(16) char sbuf[3][16384];   // [buf][x 4KB | W 12KB]

    const int tid = threadIdx.x, lane = tid & 63, cg = tid >> 6;
    const int quad = lane >> 4, l16 = lane & 15;
    const int bx = blockIdx.x;
    const int m0 = (bx >> 1) * 32;          // 32-row tile
    const int h  = bx & 1;                  // col half

    const int xrow = cg * 8 + (lane >> 3);
    const int xp   = (lane >> 1) & 3;
    const int xh   = lane & 1;
    const float* gx = x + (size_t)(m0 + xrow) * NE
                        + ((xp ^ (xrow & 3)) << 3) + (xh << 2);
    const int xl = cg * 1024 + lane * 16;
    const char* gw = imgW + (size_t)h * 12288 + (size_t)tid * 16;

    v4f acc[3];
    #pragma unroll
    for (int i = 0; i < 3; ++i) acc[i] = (v4f){0.f, 0.f, 0.f, 0.f};

    #define STAGE(ks, xb_)  do {                                          \
        gl_lds16(gx + (ks) * 32, (xb_) + xl);                             \
        const char* gws_ = gw + (size_t)(ks) * 24576;                     \
        _Pragma("unroll")                                                 \
        for (int j_ = 0; j_ < 3; ++j_)                                    \
            gl_lds16(gws_ + j_ * 4096, (xb_) + 4096 + tid * 16 + j_ * 4096); \
    } while (0)

    auto compute = [&](int ks) {
        const char* xb = sbuf[ks % 3];
        const char* wb = xb + 4096;
        const int mt = cg >> 1;
        const int wc = cg & 1;
        const int rl = mt * 16 + l16;
        const int pA = quad ^ (rl & 3);
        const float4 a0 = *(const float4*)(xb + rl * 128 + pA * 32);
        const float4 a1 = *(const float4*)(xb + rl * 128 + pA * 32 + 16);
        const float av[8] = {a0.x, a0.y, a0.z, a0.w, a1.x, a1.y, a1.z, a1.w};
        v8bf ah, al;
        #pragma unroll
        for (int i = 0; i < 8; ++i) {
            const __bf16 hv = (__bf16)av[i];
            ah[i] = hv;
            al[i] = (__bf16)(av[i] - (float)hv);
        }
        const int wo = l16 * 64 + ((quad ^ (l16 & 3)) << 4);
        #pragma unroll
        for (int j = 0; j < 3; ++j) {
            const char* base = wb + (wc * 3 + j) * 2048 + wo;
            const v8bf bh = *(const v8bf*)(base);
            const v8bf bl = *(const v8bf*)(base + 1024);
            acc[j] = MFMA_BF(ah, bh, acc[j]);
            acc[j] = MFMA_BF(ah, bl, acc[j]);
            acc[j] = MFMA_BF(al, bh, acc[j]);
        }
    };

    STAGE(0, sbuf[0]);
    STAGE(1, sbuf[1]);
    for (int ks = 0; ks < 31; ++ks) {
        SYNC_VM(WAIT_VM4);
        if (ks + 2 < 32) STAGE(ks + 2, sbuf[(ks + 2) % 3]);
        compute(ks);
    }
    SYNC_VM(WAIT_VM0);
    compute(31);
    #undef STAGE

    const int mt = cg >> 1, wc = cg & 1;
    #pragma unroll
    for (int j = 0; j < 3; ++j) {
        const int n = h * 96 + wc * 48 + j * 16 + l16;
        const float bias = (n < 64) ? bq[n] : ((n < 128) ? bk[n - 64] : bv[n - 128]);
        #pragma unroll
        for (int reg = 0; reg < 4; ++reg) {
            const int row = m0 + mt * 16 + quad * 4 + reg;
            const float v = acc[j][reg] + bias;
            if (n < 64) {
                const float s = v * QSC;
                const _Float16 hh = (_Float16)s;
                qh[(size_t)row * HS + n] = hh;
                ql[(size_t)row * HS + n] = (_Float16)(s - (float)hh);
            } else if (n < 128) {
                kf[(size_t)row * HS + n - 64] = (_Float16)v;
            } else {
                const int b2 = row >> 11, tt = row & 2047, hc = n - 128;
                vt[((size_t)(b2 * HS + hc)) * TT + tt] = (_Float16)v;
            }
        }
    }
}

// ---------------------------------------------------------------------------
// Flash attention v6 = v5 with the register allocator forced to 128 VGPR.
// Measured (r9/r10): 1024-thr attn compiles at VGPR=64 + heavy scratch spill
// (WRITE_SIZE 66MB vs 2MB of real output) whether launch_bounds is (1024,4)
// or (1024). Cause: LDS 73.7KB allows 2 blocks/CU, so the occupancy
// heuristic targets 8 waves/SIMD -> 64 VGPR. But grid = 256 blocks = 1/CU,
// so the second block never exists. Fix:
//  (a) __launch_bounds__(1024, 1): request minimum occupancy;
//  (b) smem_raw bumped to 86016 B (>80KB): 2 blocks/CU now LDS-infeasible,
//      so the heuristic itself must budget for 1 block/CU = 128 VGPR.
// v2 body needs ~104 VGPR -> no spill expected. Nothing else changed.
// ---------------------------------------------------------------------------
__global__ __launch_bounds__(1024, 1) void attn(
    const _Float16* __restrict__ qh, const _Float16* __restrict__ ql,
    const _Float16* __restrict__ kf, const _Float16* __restrict__ vt,
    float* __restrict__ out)
{
    __shared__ __align__(16) char smem_raw[86016];   // P bufs / os merge, time-shared; >80KB forces 1 blk/CU
    _Float16* ps = (_Float16*)smem_raw;
    float*    os = (float*)smem_raw;
    __shared__ float sm[16][2][16], sl[16][2][16];

    const int tid = threadIdx.x, lane = tid & 63, w = tid >> 6;   // w 0..15
    const int quad = lane >> 4, l16 = lane & 15;
    const int b = blockIdx.x & 3, pair = blockIdx.x >> 2;         // pair 0..63
    const int q0t[2] = {(127 - pair) * 16, pair * 16};
    const int ntk0 = (q0t[0] + 16 + 63) >> 6;
    const int ntk1 = (q0t[1] + 16 + 63) >> 6;
    const int total = ntk0 + ntk1;                                // == 33

    v8h Qh0[2], Qh1[2], Ql0[2], Ql1[2];
    #pragma unroll
    for (int t = 0; t < 2; ++t) {
        const size_t qrow = ((size_t)b * TT + q0t[t] + l16) * HS;
        Qh0[t] = *(const v8h*)(qh + qrow + quad * 8);
        Qh1[t] = *(const v8h*)(qh + qrow + 32 + quad * 8);
        Ql0[t] = *(const v8h*)(ql + qrow + quad * 8);
        Ql1[t] = *(const v8h*)(ql + qrow + 32 + quad * 8);
    }

    const v8h vones = {(_Float16)1.f, (_Float16)1.f, (_Float16)1.f, (_Float16)1.f,
                       (_Float16)1.f, (_Float16)1.f, (_Float16)1.f, (_Float16)1.f};

    float mr0[4] = {-3e38f, -3e38f, -3e38f, -3e38f};
    float mr1[4] = {-3e38f, -3e38f, -3e38f, -3e38f};
    v4f o0[4], o1[4], l40, l41;
    #pragma unroll
    for (int i = 0; i < 4; ++i) {
        o0[i] = (v4f){0.f, 0.f, 0.f, 0.f};
        o1[i] = (v4f){0.f, 0.f, 0.f, 0.f};
    }
    l40 = (v4f){0.f, 0.f, 0.f, 0.f};
    l41 = (v4f){0.f, 0.f, 0.f, 0.f};

    _Float16* pw = ps + w * (16 * 72);     // 16 waves x 2304 B = 36864 B

    auto doChunk = [&](int j0, int q0c, int t,
                       float (&mrow)[4], v4f (&o)[4], v4f &o4) {
        v8h Kf[8], Vf[8];
        #pragma unroll
        for (int nt = 0; nt < 4; ++nt) {
            const size_t krow = ((size_t)b * TT + j0 + nt * 16 + l16) * HS;
            Kf[nt * 2]     = *(const v8h*)(kf + krow + quad * 8);
            Kf[nt * 2 + 1] = *(const v8h*)(kf + krow + 32 + quad * 8);
        }
        #pragma unroll
        for (int nt = 0; nt < 4; ++nt) {
            const size_t vrow = ((size_t)(b * HS + nt * 16 + l16)) * TT + j0;
            Vf[nt * 2]     = *(const v8h*)(vt + vrow + quad * 8);
            Vf[nt * 2 + 1] = *(const v8h*)(vt + vrow + 32 + quad * 8);
        }
        v4f s[4];
        #pragma unroll
        for (int i = 0; i < 4; ++i) s[i] = (v4f){0.f, 0.f, 0.f, 0.f};
        #pragma unroll
        for (int nt = 0; nt < 4; ++nt) {
            s[nt] = MFMA_F16(Qh0[t], Kf[nt * 2],     s[nt]);
            s[nt] = MFMA_F16(Qh1[t], Kf[nt * 2 + 1], s[nt]);
            s[nt] = MFMA_F16(Ql0[t], Kf[nt * 2],     s[nt]);
            s[nt] = MFMA_F16(Ql1[t], Kf[nt * 2 + 1], s[nt]);
        }
        const int irow = q0c + quad * 4;
        float mx[4] = {-3e38f, -3e38f, -3e38f, -3e38f};
        #pragma unroll
        for (int nt = 0; nt < 4; ++nt)
            #pragma unroll
            for (int reg = 0; reg < 4; ++reg) {
                if (j0 + nt * 16 + l16 > irow + reg) s[nt][reg] = -3e38f;
                mx[reg] = fmaxf(mx[reg], s[nt][reg]);
            }
        #pragma unroll
        for (int off = 8; off; off >>= 1)
            #pragma unroll
            for (int reg = 0; reg < 4; ++reg)
                mx[reg] = fmaxf(mx[reg], __shfl_xor(mx[reg], off));
        float al[4];
        #pragma unroll
        for (int reg = 0; reg < 4; ++reg) {
            const float mn = fmaxf(mrow[reg], mx[reg]);
            al[reg] = exp2f(mrow[reg] - mn);
            mrow[reg] = mn;
        }
        #pragma unroll
        for (int nt = 0; nt < 4; ++nt)
            #pragma unroll
            for (int reg = 0; reg < 4; ++reg) {
                const float p = (j0 + nt * 16 + l16 > irow + reg)
                                    ? 0.f : exp2f(s[nt][reg] - mrow[reg]);
                pw[(quad * 4 + reg) * 72 + nt * 16 + l16] = (_Float16)p;
            }
        #pragma unroll
        for (int nt = 0; nt < 4; ++nt)
            #pragma unroll
            for (int reg = 0; reg < 4; ++reg)
                o[nt][reg] *= al[reg];
        #pragma unroll
        for (int reg = 0; reg < 4; ++reg)
            o4[reg] *= al[reg];
        const v8h Pa0 = *(const v8h*)(pw + l16 * 72 + quad * 8);
        const v8h Pa1 = *(const v8h*)(pw + l16 * 72 + 32 + quad * 8);
        #pragma unroll
        for (int nt = 0; nt < 4; ++nt) {
            o[nt] = MFMA_F16(Pa0, Vf[nt * 2],     o[nt]);
            o[nt] = MFMA_F16(Pa1, Vf[nt * 2 + 1], o[nt]);
        }
        o4 = MFMA_F16(Pa0, vones, o4);
        o4 = MFMA_F16(Pa1, vones, o4);
    };

    for (int c = w; c < total; c += 16) {
        if (c < ntk0) doChunk(c * 64,          q0t[0], 0, mr0, o0, l40);
        else          doChunk((c - ntk0) * 64, q0t[1], 1, mr1, o1, l41);
    }

    if (l16 == 0) {
        #pragma unroll
        for (int reg = 0; reg < 4; ++reg) {
            sm[w][0][quad * 4 + reg] = mr0[reg];
            sl[w][0][quad * 4 + reg] = l40[reg];
            sm[w][1][quad * 4 + reg] = mr1[reg];
            sl[w][1][quad * 4 + reg] = l41[reg];
        }
    }
    __syncthreads();

    // --- two-pass exact merge: pass p has waves p*8..p*8+7 write os, then
    // all threads accumulate their 8 slots. Same global M everywhere. ---
    float val2[2] = {0.f, 0.f};
    #pragma unroll
    for (int pass = 0; pass < 2; ++pass) {
        if ((w >> 3) == pass) {
            #pragma unroll
            for (int t = 0; t < 2; ++t) {
                float sc[4];
                #pragma unroll
                for (int reg = 0; reg < 4; ++reg) {
                    const int r = quad * 4 + reg;
                    float M = sm[0][t][r];
                    #pragma unroll
                    for (int i = 1; i < 16; ++i) M = fmaxf(M, sm[i][t][r]);
                    const float mw = t ? mr1[reg] : mr0[reg];
                    sc[reg] = exp2f(mw - M);
                }
                float* ow = os + (size_t)((w & 7) * 2 + t) * (16 * 68);
                #pragma unroll
                for (int nt = 0; nt < 4; ++nt)
                    #pragma unroll
                    for (int reg = 0; reg < 4; ++reg) {
                        const v4f& oo = t ? o1[nt] : o0[nt];
                        ow[(quad * 4 + reg) * 68 + nt * 16 + l16] = oo[reg] * sc[reg];
                    }
            }
        }
        __syncthreads();
        {
            const int t = w >> 3;
            #pragma unroll
            for (int kk = 0; kk < 2; ++kk) {
                const int m = (w * 2 + kk) & 15;
                #pragma unroll
                for (int i = 0; i < 8; ++i)
                    val2[kk] += os[(size_t)(i * 2 + t) * (16 * 68) + m * 68 + lane];
            }
        }
        __syncthreads();   // reads done before next pass overwrites
    }

    {
        const int t = w >> 3;
        #pragma unroll
        for (int kk = 0; kk < 2; ++kk) {
            const int m = (w * 2 + kk) & 15;
            float M = sm[0][t][m];
            #pragma unroll
            for (int i = 1; i < 16; ++i) M = fmaxf(M, sm[i][t][m]);
            float L = 0.f;
            #pragma unroll
            for (int i = 0; i < 16; ++i)
                L += sl[i][t][m] * exp2f(sm[i][t][m] - M);
            out[((size_t)b * TT + q0t[t] + m) * HS + lane] = val2[kk] / L;
        }
    }
}

// ---------------------------------------------------------------------------
extern "C" void kernel_launch(void* const* d_in, const int* in_sizes, int n_in,
                              void* d_out, int out_size, void* d_ws, size_t ws_size,
                              hipStream_t stream)
{
    const float* x  = (const float*)d_in[0];
    const float* Wq = (const float*)d_in[1];
    const float* bq = (const float*)d_in[2];
    const float* Wk = (const float*)d_in[3];
    const float* bk = (const float*)d_in[4];
    const float* Wv = (const float*)d_in[5];
    const float* bv = (const float*)d_in[6];
    float* out = (float*)d_out;

    const int rows = in_sizes[0] / NE;   // 8192
    char* p = (char*)d_ws;
    char* imgW = p;                           p += (size_t)32 * 24576;      // 768 KB
    _Float16* qhb = (_Float16*)p;             p += (size_t)rows * HS * 2;
    _Float16* qlb = (_Float16*)p;             p += (size_t)rows * HS * 2;
    _Float16* kfb = (_Float16*)p;             p += (size_t)rows * HS * 2;
    _Float16* vtb = (_Float16*)p;             p += (size_t)rows * HS * 2;

    prep_w<<<dim3(16, 3), 256, 0, stream>>>(Wq, Wk, Wv, imgW);
    proj<<<rows / 16, 256, 0, stream>>>(x, imgW, bq, bk, bv,
                                        qhb, qlb, kfb, vtb);
    attn<<<rows / 32, 1024, 0, stream>>>(qhb, qlb, kfb, vtb, out);
}

// Round 12
// 139.182 us; speedup vs baseline: 1.1084x; 1.0816x over previous
//
#include <hip/hip_runtime.h>
#include <math.h>

// B=4, T=2048, N_EMBD=1024, HEAD=64.
// Reference multiplies scores by sqrt(64)=8; we fold 8*log2(e) into q and use exp2.
#define NE 1024
#define HS 64
#define TT 2048
#define QSC 11.541560327111707f   // 8 * log2(e)

typedef __bf16    v8bf __attribute__((ext_vector_type(8)));
typedef _Float16  v8h  __attribute__((ext_vector_type(8)));
typedef float     v4f  __attribute__((ext_vector_type(4)));

#define MFMA_BF(a, b, c)  __builtin_amdgcn_mfma_f32_16x16x32_bf16((a), (b), (c), 0, 0, 0)
#define MFMA_F16(a, b, c) __builtin_amdgcn_mfma_f32_16x16x32_f16((a), (b), (c), 0, 0, 0)

// async global->LDS DMA (lands at wave-uniform base + lane*size)
__device__ __forceinline__ void gl_lds16(const void* g, void* l) {
    __builtin_amdgcn_global_load_lds(
        (const __attribute__((address_space(1))) unsigned int*)g,
        (__attribute__((address_space(3))) unsigned int*)l, 16, 0, 0);
}

// raw barrier with manual vmcnt: NO compiler-inserted vmcnt(0) drain.
#define SYNC_VM(imm) do {                                   \
    __asm__ __volatile__("" ::: "memory");                  \
    __builtin_amdgcn_s_waitcnt(imm);                        \
    __builtin_amdgcn_s_barrier();                           \
    __asm__ __volatile__("" ::: "memory");                  \
} while (0)
#define WAIT_VM4  0x0F74   // vmcnt(4)
#define WAIT_VM0  0x0F70   // vmcnt(0)

// ---------------------------------------------------------------------------
// prep_w: unchanged.
// ---------------------------------------------------------------------------
__global__ __launch_bounds__(256) void prep_w(
    const float* __restrict__ Wq, const float* __restrict__ Wk,
    const float* __restrict__ Wv, char* __restrict__ imgW)
{
    __shared__ float t[64][65];
    const int bx = blockIdx.x, by = blockIdx.y;
    const float* W = (by == 0) ? Wq : ((by == 1) ? Wk : Wv);
    const int tid = threadIdx.x;
    const int cc = tid & 63, r4 = tid >> 6;
    #pragma unroll
    for (int p = 0; p < 16; ++p) {
        const int k = p * 4 + r4;
        t[k][cc] = W[(size_t)(bx * 64 + k) * HS + cc];   // coalesced
    }
    __syncthreads();
    #pragma unroll
    for (int e = 0; e < 4; ++e) {
        const int chunk = tid + e * 256;
        const int s2   = chunk >> 9;
        const int rem  = chunk & 511;
        const int ctl  = rem >> 7;
        const int rem2 = rem & 127;
        const int pl   = rem2 >> 6;
        const int rem3 = rem2 & 63;
        const int c    = rem3 >> 2;
        const int p16  = rem3 & 3;
        const int kb   = s2 * 32 + ((p16 ^ (c & 3)) << 3);
        const int ncol = ctl * 16 + c;
        v8bf o;
        #pragma unroll
        for (int j = 0; j < 8; ++j) {
            const float v = t[kb + j][ncol];
            const __bf16 h = (__bf16)v;
            o[j] = pl ? (__bf16)(v - (float)h) : h;
        }
        *(v8bf*)(imgW + (size_t)(bx * 2 + s2) * 24576
                 + (by * 4 + ctl) * 2048 + pl * 1024 + c * 64 + p16 * 16) = o;
    }
}

// ---------------------------------------------------------------------------
// Projection GEMM v2 (unchanged): 512 blocks x 256 thr, 32x96 tile.
// ---------------------------------------------------------------------------
__global__ __launch_bounds__(256, 2) void proj(
    const float* __restrict__ x, const char* __restrict__ imgW,
    const float* __restrict__ bq, const float* __restrict__ bk,
    const float* __restrict__ bv,
    _Float16* __restrict__ qh, _Float16* __restrict__ ql,
    _Float16* __restrict__ kf, _Float16* __restrict__ vt)
{
    __shared__ __align__(16) char sbuf[3][16384];   // [buf][x 4KB | W 12KB]

    const int tid = threadIdx.x, lane = tid & 63, cg = tid >> 6;
    const int quad = lane >> 4, l16 = lane & 15;
    const int bx = blockIdx.x;
    const int m0 = (bx >> 1) * 32;          // 32-row tile
    const int h  = bx & 1;                  // col half

    const int xrow = cg * 8 + (lane >> 3);
    const int xp   = (lane >> 1) & 3;
    const int xh   = lane & 1;
    const float* gx = x + (size_t)(m0 + xrow) * NE
                        + ((xp ^ (xrow & 3)) << 3) + (xh << 2);
    const int xl = cg * 1024 + lane * 16;
    const char* gw = imgW + (size_t)h * 12288 + (size_t)tid * 16;

    v4f acc[3];
    #pragma unroll
    for (int i = 0; i < 3; ++i) acc[i] = (v4f){0.f, 0.f, 0.f, 0.f};

    #define STAGE(ks, xb_)  do {                                          \
        gl_lds16(gx + (ks) * 32, (xb_) + xl);                             \
        const char* gws_ = gw + (size_t)(ks) * 24576;                     \
        _Pragma("unroll")                                                 \
        for (int j_ = 0; j_ < 3; ++j_)                                    \
            gl_lds16(gws_ + j_ * 4096, (xb_) + 4096 + tid * 16 + j_ * 4096); \
    } while (0)

    auto compute = [&](int ks) {
        const char* xb = sbuf[ks % 3];
        const char* wb = xb + 4096;
        const int mt = cg >> 1;
        const int wc = cg & 1;
        const int rl = mt * 16 + l16;
        const int pA = quad ^ (rl & 3);
        const float4 a0 = *(const float4*)(xb + rl * 128 + pA * 32);
        const float4 a1 = *(const float4*)(xb + rl * 128 + pA * 32 + 16);
        const float av[8] = {a0.x, a0.y, a0.z, a0.w, a1.x, a1.y, a1.z, a1.w};
        v8bf ah, al;
        #pragma unroll
        for (int i = 0; i < 8; ++i) {
            const __bf16 hv = (__bf16)av[i];
            ah[i] = hv;
            al[i] = (__bf16)(av[i] - (float)hv);
        }
        const int wo = l16 * 64 + ((quad ^ (l16 & 3)) << 4);
        #pragma unroll
        for (int j = 0; j < 3; ++j) {
            const char* base = wb + (wc * 3 + j) * 2048 + wo;
            const v8bf bh = *(const v8bf*)(base);
            const v8bf bl = *(const v8bf*)(base + 1024);
            acc[j] = MFMA_BF(ah, bh, acc[j]);
            acc[j] = MFMA_BF(ah, bl, acc[j]);
            acc[j] = MFMA_BF(al, bh, acc[j]);
        }
    };

    STAGE(0, sbuf[0]);
    STAGE(1, sbuf[1]);
    for (int ks = 0; ks < 31; ++ks) {
        SYNC_VM(WAIT_VM4);
        if (ks + 2 < 32) STAGE(ks + 2, sbuf[(ks + 2) % 3]);
        compute(ks);
    }
    SYNC_VM(WAIT_VM0);
    compute(31);
    #undef STAGE

    const int mt = cg >> 1, wc = cg & 1;
    #pragma unroll
    for (int j = 0; j < 3; ++j) {
        const int n = h * 96 + wc * 48 + j * 16 + l16;
        const float bias = (n < 64) ? bq[n] : ((n < 128) ? bk[n - 64] : bv[n - 128]);
        #pragma unroll
        for (int reg = 0; reg < 4; ++reg) {
            const int row = m0 + mt * 16 + quad * 4 + reg;
            const float v = acc[j][reg] + bias;
            if (n < 64) {
                const float s = v * QSC;
                const _Float16 hh = (_Float16)s;
                qh[(size_t)row * HS + n] = hh;
                ql[(size_t)row * HS + n] = (_Float16)(s - (float)hh);
            } else if (n < 128) {
                kf[(size_t)row * HS + n - 64] = (_Float16)v;
            } else {
                const int b2 = row >> 11, tt = row & 2047, hc = n - 128;
                vt[((size_t)(b2 * HS + hc)) * TT + tt] = (_Float16)v;
            }
        }
    }
}

// ---------------------------------------------------------------------------
// Flash attention v7: split-pair TLP. The 1024-thread route spills (r9-r11:
// VGPR pinned at 64, 66MB scratch, 3 configs). Return to the r6-proven
// 512-thread codegen (VGPR 104, no spill) and get 4 waves/SIMD via grid:
// 512 blocks = 4 batches x 64 pairs x 2 halves -> 2 blocks/CU co-resident
// (LDS 72KB x2 = 144 <= 160KB, VGPR 104 <= 128). Each half-block processes
// the pair's chunks of one parity (16/17 chunks, deterministically balanced)
// and writes flash partials (M, L, unnormalized O) to workspace; a light
// merge kernel combines the two halves exactly (exp2f(-3e38-M)=0 handles
// single-sided tiles).
// ---------------------------------------------------------------------------
__global__ __launch_bounds__(512, 2) void attn(
    const _Float16* __restrict__ qh, const _Float16* __restrict__ ql,
    const _Float16* __restrict__ kf, const _Float16* __restrict__ vt,
    float* __restrict__ pM, float* __restrict__ pL, float* __restrict__ pO)
{
    __shared__ __align__(16) char smem_raw[69632];
    _Float16* ps = (_Float16*)smem_raw;
    float*    os = (float*)smem_raw;
    __shared__ float sm[8][2][16], sl[8][2][16];

    const int tid = threadIdx.x, lane = tid & 63, w = tid >> 6;
    const int quad = lane >> 4, l16 = lane & 15;
    const int bx = blockIdx.x;
    const int b = bx & 3, half = (bx >> 2) & 1, pair = bx >> 3;   // pair 0..63
    const int q0t[2] = {(127 - pair) * 16, pair * 16};
    const int ntk0 = (q0t[0] + 16 + 63) >> 6;
    const int ntk1 = (q0t[1] + 16 + 63) >> 6;
    const int total = ntk0 + ntk1;                                // == 33

    v8h Qh0[2], Qh1[2], Ql0[2], Ql1[2];
    #pragma unroll
    for (int t = 0; t < 2; ++t) {
        const size_t qrow = ((size_t)b * TT + q0t[t] + l16) * HS;
        Qh0[t] = *(const v8h*)(qh + qrow + quad * 8);
        Qh1[t] = *(const v8h*)(qh + qrow + 32 + quad * 8);
        Ql0[t] = *(const v8h*)(ql + qrow + quad * 8);
        Ql1[t] = *(const v8h*)(ql + qrow + 32 + quad * 8);
    }

    const v8h vones = {(_Float16)1.f, (_Float16)1.f, (_Float16)1.f, (_Float16)1.f,
                       (_Float16)1.f, (_Float16)1.f, (_Float16)1.f, (_Float16)1.f};

    float mr0[4] = {-3e38f, -3e38f, -3e38f, -3e38f};
    float mr1[4] = {-3e38f, -3e38f, -3e38f, -3e38f};
    v4f o0[4], o1[4], l40, l41;
    #pragma unroll
    for (int i = 0; i < 4; ++i) {
        o0[i] = (v4f){0.f, 0.f, 0.f, 0.f};
        o1[i] = (v4f){0.f, 0.f, 0.f, 0.f};
    }
    l40 = (v4f){0.f, 0.f, 0.f, 0.f};
    l41 = (v4f){0.f, 0.f, 0.f, 0.f};

    _Float16* pw = ps + w * (16 * 72);

    auto doChunk = [&](int j0, int q0c, int t,
                       float (&mrow)[4], v4f (&o)[4], v4f &o4) {
        v8h Kf[8], Vf[8];
        #pragma unroll
        for (int nt = 0; nt < 4; ++nt) {
            const size_t krow = ((size_t)b * TT + j0 + nt * 16 + l16) * HS;
            Kf[nt * 2]     = *(const v8h*)(kf + krow + quad * 8);
            Kf[nt * 2 + 1] = *(const v8h*)(kf + krow + 32 + quad * 8);
        }
        #pragma unroll
        for (int nt = 0; nt < 4; ++nt) {
            const size_t vrow = ((size_t)(b * HS + nt * 16 + l16)) * TT + j0;
            Vf[nt * 2]     = *(const v8h*)(vt + vrow + quad * 8);
            Vf[nt * 2 + 1] = *(const v8h*)(vt + vrow + 32 + quad * 8);
        }
        v4f s[4];
        #pragma unroll
        for (int i = 0; i < 4; ++i) s[i] = (v4f){0.f, 0.f, 0.f, 0.f};
        #pragma unroll
        for (int nt = 0; nt < 4; ++nt) {
            s[nt] = MFMA_F16(Qh0[t], Kf[nt * 2],     s[nt]);
            s[nt] = MFMA_F16(Qh1[t], Kf[nt * 2 + 1], s[nt]);
            s[nt] = MFMA_F16(Ql0[t], Kf[nt * 2],     s[nt]);
            s[nt] = MFMA_F16(Ql1[t], Kf[nt * 2 + 1], s[nt]);
        }
        const int irow = q0c + quad * 4;
        float mx[4] = {-3e38f, -3e38f, -3e38f, -3e38f};
        #pragma unroll
        for (int nt = 0; nt < 4; ++nt)
            #pragma unroll
            for (int reg = 0; reg < 4; ++reg) {
                if (j0 + nt * 16 + l16 > irow + reg) s[nt][reg] = -3e38f;
                mx[reg] = fmaxf(mx[reg], s[nt][reg]);
            }
        #pragma unroll
        for (int off = 8; off; off >>= 1)
            #pragma unroll
            for (int reg = 0; reg < 4; ++reg)
                mx[reg] = fmaxf(mx[reg], __shfl_xor(mx[reg], off));
        float al[4];
        #pragma unroll
        for (int reg = 0; reg < 4; ++reg) {
            const float mn = fmaxf(mrow[reg], mx[reg]);
            al[reg] = exp2f(mrow[reg] - mn);
            mrow[reg] = mn;
        }
        #pragma unroll
        for (int nt = 0; nt < 4; ++nt)
            #pragma unroll
            for (int reg = 0; reg < 4; ++reg) {
                const float p = (j0 + nt * 16 + l16 > irow + reg)
                                    ? 0.f : exp2f(s[nt][reg] - mrow[reg]);
                pw[(quad * 4 + reg) * 72 + nt * 16 + l16] = (_Float16)p;
            }
        #pragma unroll
        for (int nt = 0; nt < 4; ++nt)
            #pragma unroll
            for (int reg = 0; reg < 4; ++reg)
                o[nt][reg] *= al[reg];
        #pragma unroll
        for (int reg = 0; reg < 4; ++reg)
            o4[reg] *= al[reg];
        const v8h Pa0 = *(const v8h*)(pw + l16 * 72 + quad * 8);
        const v8h Pa1 = *(const v8h*)(pw + l16 * 72 + 32 + quad * 8);
        #pragma unroll
        for (int nt = 0; nt < 4; ++nt) {
            o[nt] = MFMA_F16(Pa0, Vf[nt * 2],     o[nt]);
            o[nt] = MFMA_F16(Pa1, Vf[nt * 2 + 1], o[nt]);
        }
        o4 = MFMA_F16(Pa0, vones, o4);
        o4 = MFMA_F16(Pa1, vones, o4);
    };

    // this half-block: chunks with parity == half; wave w starts at 2w+half
    for (int c = 2 * w + half; c < total; c += 16) {
        if (c < ntk0) doChunk(c * 64,          q0t[0], 0, mr0, o0, l40);
        else          doChunk((c - ntk0) * 64, q0t[1], 1, mr1, o1, l41);
    }

    if (l16 == 0) {
        #pragma unroll
        for (int reg = 0; reg < 4; ++reg) {
            sm[w][0][quad * 4 + reg] = mr0[reg];
            sl[w][0][quad * 4 + reg] = l40[reg];
            sm[w][1][quad * 4 + reg] = mr1[reg];
            sl[w][1][quad * 4 + reg] = l41[reg];
        }
    }
    __syncthreads();

    #pragma unroll
    for (int t = 0; t < 2; ++t) {
        float sc[4];
        #pragma unroll
        for (int reg = 0; reg < 4; ++reg) {
            const int r = quad * 4 + reg;
            float M = sm[0][t][r];
            #pragma unroll
            for (int i = 1; i < 8; ++i) M = fmaxf(M, sm[i][t][r]);
            const float mw = t ? mr1[reg] : mr0[reg];
            sc[reg] = exp2f(mw - M);
        }
        float* ow = os + (size_t)(w * 2 + t) * (16 * 68);
        #pragma unroll
        for (int nt = 0; nt < 4; ++nt)
            #pragma unroll
            for (int reg = 0; reg < 4; ++reg) {
                const v4f& oo = t ? o1[nt] : o0[nt];
                ow[(quad * 4 + reg) * 68 + nt * 16 + l16] = oo[reg] * sc[reg];
            }
    }
    __syncthreads();

    #pragma unroll
    for (int kk = 0; kk < 4; ++kk) {
        const int g = w * 4 + kk;
        const int t = g >> 4, m = g & 15;
        float M = sm[0][t][m];
        #pragma unroll
        for (int i = 1; i < 8; ++i) M = fmaxf(M, sm[i][t][m]);
        float L = 0.f, val = 0.f;
        #pragma unroll
        for (int i = 0; i < 8; ++i) {
            L   += sl[i][t][m] * exp2f(sm[i][t][m] - M);
            val += os[(size_t)(i * 2 + t) * (16 * 68) + m * 68 + lane];
        }
        const int tile = q0t[t] >> 4;
        const size_t pb = ((size_t)(half * 4 + b) * 128 + tile);
        pO[pb * 1024 + m * 64 + lane] = val;
        if (lane == 0) { pM[pb * 16 + m] = M; pL[pb * 16 + m] = L; }
    }
}

// ---------------------------------------------------------------------------
// merge: combine the two half-partials exactly. 2048 blocks x 256 thr,
// one thread per (row, lane) output element.
// ---------------------------------------------------------------------------
__global__ __launch_bounds__(256) void merge(
    const float* __restrict__ pM, const float* __restrict__ pL,
    const float* __restrict__ pO, float* __restrict__ out)
{
    const int gid = blockIdx.x * 256 + threadIdx.x;   // 0..524287
    const int lane = gid & 63;
    const int r = gid >> 6;                            // row 0..8191
    const int b = r >> 11, tt = r & 2047;
    const int tile = tt >> 4, m = tt & 15;
    const size_t p0 = (size_t)(0 * 4 + b) * 128 + tile;
    const size_t p1 = (size_t)(1 * 4 + b) * 128 + tile;
    const float M0 = pM[p0 * 16 + m], M1 = pM[p1 * 16 + m];
    const float M = fmaxf(M0, M1);
    const float a0 = exp2f(M0 - M), a1 = exp2f(M1 - M);
    const float L = pL[p0 * 16 + m] * a0 + pL[p1 * 16 + m] * a1;
    const float v = pO[p0 * 1024 + m * 64 + lane] * a0
                  + pO[p1 * 1024 + m * 64 + lane] * a1;
    out[(size_t)r * HS + lane] = v / L;
}

// ---------------------------------------------------------------------------
extern "C" void kernel_launch(void* const* d_in, const int* in_sizes, int n_in,
                              void* d_out, int out_size, void* d_ws, size_t ws_size,
                              hipStream_t stream)
{
    const float* x  = (const float*)d_in[0];
    const float* Wq = (const float*)d_in[1];
    const float* bq = (const float*)d_in[2];
    const float* Wk = (const float*)d_in[3];
    const float* bk = (const float*)d_in[4];
    const float* Wv = (const float*)d_in[5];
    const float* bv = (const float*)d_in[6];
    float* out = (float*)d_out;

    const int rows = in_sizes[0] / NE;   // 8192
    char* p = (char*)d_ws;
    char* imgW = p;                           p += (size_t)32 * 24576;      // 768 KB
    _Float16* qhb = (_Float16*)p;             p += (size_t)rows * HS * 2;
    _Float16* qlb = (_Float16*)p;             p += (size_t)rows * HS * 2;
    _Float16* kfb = (_Float16*)p;             p += (size_t)rows * HS * 2;
    _Float16* vtb = (_Float16*)p;             p += (size_t)rows * HS * 2;
    float* pM = (float*)p;                    p += (size_t)2 * 4 * 128 * 16 * 4;       // 64 KB
    float* pL = (float*)p;                    p += (size_t)2 * 4 * 128 * 16 * 4;       // 64 KB
    float* pO = (float*)p;                    p += (size_t)2 * 4 * 128 * 16 * 64 * 4;  // 4 MB

    prep_w<<<dim3(16, 3), 256, 0, stream>>>(Wq, Wk, Wv, imgW);
    proj<<<rows / 16, 256, 0, stream>>>(x, imgW, bq, bk, bv,
                                        qhb, qlb, kfb, vtb);
    attn<<<rows / 16, 512, 0, stream>>>(qhb, qlb, kfb, vtb, pM, pL, pO);
    merge<<<(rows * HS) / 256, 256, 0, stream>>>(pM, pL, pO, out);
}

// Round 13
// 128.670 us; speedup vs baseline: 1.1990x; 1.0817x over previous
//
#include <hip/hip_runtime.h>
#include <math.h>

// B=4, T=2048, N_EMBD=1024, HEAD=64.
// Reference multiplies scores by sqrt(64)=8; we fold 8*log2(e) into q and use exp2.
#define NE 1024
#define HS 64
#define TT 2048
#define QSC 11.541560327111707f   // 8 * log2(e)

typedef __bf16    v8bf __attribute__((ext_vector_type(8)));
typedef _Float16  v8h  __attribute__((ext_vector_type(8)));
typedef float     v4f  __attribute__((ext_vector_type(4)));

#define MFMA_BF(a, b, c)  __builtin_amdgcn_mfma_f32_16x16x32_bf16((a), (b), (c), 0, 0, 0)
#define MFMA_F16(a, b, c) __builtin_amdgcn_mfma_f32_16x16x32_f16((a), (b), (c), 0, 0, 0)

// async global->LDS DMA (lands at wave-uniform base + lane*size)
__device__ __forceinline__ void gl_lds16(const void* g, void* l) {
    __builtin_amdgcn_global_load_lds(
        (const __attribute__((address_space(1))) unsigned int*)g,
        (__attribute__((address_space(3))) unsigned int*)l, 16, 0, 0);
}

// raw barrier with manual vmcnt: NO compiler-inserted vmcnt(0) drain.
#define SYNC_VM(imm) do {                                   \
    __asm__ __volatile__("" ::: "memory");                  \
    __builtin_amdgcn_s_waitcnt(imm);                        \
    __builtin_amdgcn_s_barrier();                           \
    __asm__ __volatile__("" ::: "memory");                  \
} while (0)
#define WAIT_VM4  0x0F74   // vmcnt(4)
#define WAIT_VM0  0x0F70   // vmcnt(0)

// ---------------------------------------------------------------------------
// prep_w: unchanged.
// ---------------------------------------------------------------------------
__global__ __launch_bounds__(256) void prep_w(
    const float* __restrict__ Wq, const float* __restrict__ Wk,
    const float* __restrict__ Wv, char* __restrict__ imgW)
{
    __shared__ float t[64][65];
    const int bx = blockIdx.x, by = blockIdx.y;
    const float* W = (by == 0) ? Wq : ((by == 1) ? Wk : Wv);
    const int tid = threadIdx.x;
    const int cc = tid & 63, r4 = tid >> 6;
    #pragma unroll
    for (int p = 0; p < 16; ++p) {
        const int k = p * 4 + r4;
        t[k][cc] = W[(size_t)(bx * 64 + k) * HS + cc];   // coalesced
    }
    __syncthreads();
    #pragma unroll
    for (int e = 0; e < 4; ++e) {
        const int chunk = tid + e * 256;
        const int s2   = chunk >> 9;
        const int rem  = chunk & 511;
        const int ctl  = rem >> 7;
        const int rem2 = rem & 127;
        const int pl   = rem2 >> 6;
        const int rem3 = rem2 & 63;
        const int c    = rem3 >> 2;
        const int p16  = rem3 & 3;
        const int kb   = s2 * 32 + ((p16 ^ (c & 3)) << 3);
        const int ncol = ctl * 16 + c;
        v8bf o;
        #pragma unroll
        for (int j = 0; j < 8; ++j) {
            const float v = t[kb + j][ncol];
            const __bf16 h = (__bf16)v;
            o[j] = pl ? (__bf16)(v - (float)h) : h;
        }
        *(v8bf*)(imgW + (size_t)(bx * 2 + s2) * 24576
                 + (by * 4 + ctl) * 2048 + pl * 1024 + c * 64 + p16 * 16) = o;
    }
}

// ---------------------------------------------------------------------------
// Projection GEMM v2 (unchanged, in the r3-best build): 512 blocks x 256 thr,
// block = 32 rows x 96 cols, triple-buffered DMA staging, vmcnt(4).
// ---------------------------------------------------------------------------
__global__ __launch_bounds__(256, 2) void proj(
    const float* __restrict__ x, const char* __restrict__ imgW,
    const float* __restrict__ bq, const float* __restrict__ bk,
    const float* __restrict__ bv,
    _Float16* __restrict__ qh, _Float16* __restrict__ ql,
    _Float16* __restrict__ kf, _Float16* __restrict__ vt)
{
    __shared__ __align__(16) char sbuf[3][16384];   // [buf][x 4KB | W 12KB]

    const int tid = threadIdx.x, lane = tid & 63, cg = tid >> 6;
    const int quad = lane >> 4, l16 = lane & 15;
    const int bx = blockIdx.x;
    const int m0 = (bx >> 1) * 32;          // 32-row tile
    const int h  = bx & 1;                  // col half

    const int xrow = cg * 8 + (lane >> 3);
    const int xp   = (lane >> 1) & 3;
    const int xh   = lane & 1;
    const float* gx = x + (size_t)(m0 + xrow) * NE
                        + ((xp ^ (xrow & 3)) << 3) + (xh << 2);
    const int xl = cg * 1024 + lane * 16;
    const char* gw = imgW + (size_t)h * 12288 + (size_t)tid * 16;

    v4f acc[3];
    #pragma unroll
    for (int i = 0; i < 3; ++i) acc[i] = (v4f){0.f, 0.f, 0.f, 0.f};

    #define STAGE(ks, xb_)  do {                                          \
        gl_lds16(gx + (ks) * 32, (xb_) + xl);                             \
        const char* gws_ = gw + (size_t)(ks) * 24576;                     \
        _Pragma("unroll")                                                 \
        for (int j_ = 0; j_ < 3; ++j_)                                    \
            gl_lds16(gws_ + j_ * 4096, (xb_) + 4096 + tid * 16 + j_ * 4096); \
    } while (0)

    auto compute = [&](int ks) {
        const char* xb = sbuf[ks % 3];
        const char* wb = xb + 4096;
        const int mt = cg >> 1;
        const int wc = cg & 1;
        const int rl = mt * 16 + l16;
        const int pA = quad ^ (rl & 3);
        const float4 a0 = *(const float4*)(xb + rl * 128 + pA * 32);
        const float4 a1 = *(const float4*)(xb + rl * 128 + pA * 32 + 16);
        const float av[8] = {a0.x, a0.y, a0.z, a0.w, a1.x, a1.y, a1.z, a1.w};
        v8bf ah, al;
        #pragma unroll
        for (int i = 0; i < 8; ++i) {
            const __bf16 hv = (__bf16)av[i];
            ah[i] = hv;
            al[i] = (__bf16)(av[i] - (float)hv);
        }
        const int wo = l16 * 64 + ((quad ^ (l16 & 3)) << 4);
        #pragma unroll
        for (int j = 0; j < 3; ++j) {
            const char* base = wb + (wc * 3 + j) * 2048 + wo;
            const v8bf bh = *(const v8bf*)(base);
            const v8bf bl = *(const v8bf*)(base + 1024);
            acc[j] = MFMA_BF(ah, bh, acc[j]);
            acc[j] = MFMA_BF(ah, bl, acc[j]);
            acc[j] = MFMA_BF(al, bh, acc[j]);
        }
    };

    STAGE(0, sbuf[0]);
    STAGE(1, sbuf[1]);
    for (int ks = 0; ks < 31; ++ks) {
        SYNC_VM(WAIT_VM4);
        if (ks + 2 < 32) STAGE(ks + 2, sbuf[(ks + 2) % 3]);
        compute(ks);
    }
    SYNC_VM(WAIT_VM0);
    compute(31);
    #undef STAGE

    const int mt = cg >> 1, wc = cg & 1;
    #pragma unroll
    for (int j = 0; j < 3; ++j) {
        const int n = h * 96 + wc * 48 + j * 16 + l16;
        const float bias = (n < 64) ? bq[n] : ((n < 128) ? bk[n - 64] : bv[n - 128]);
        #pragma unroll
        for (int reg = 0; reg < 4; ++reg) {
            const int row = m0 + mt * 16 + quad * 4 + reg;
            const float v = acc[j][reg] + bias;
            if (n < 64) {
                const float s = v * QSC;
                const _Float16 hh = (_Float16)s;
                qh[(size_t)row * HS + n] = hh;
                ql[(size_t)row * HS + n] = (_Float16)(s - (float)hh);
            } else if (n < 128) {
                kf[(size_t)row * HS + n - 64] = (_Float16)v;
            } else {
                const int b2 = row >> 11, tt = row & 2047, hc = n - 128;
                vt[((size_t)(b2 * HS + hc)) * TT + tt] = (_Float16)v;
            }
        }
    }
}

// ---------------------------------------------------------------------------
// Flash attention v8 = r3-best structure (v2 body + K register double-buffer,
// 256 blocks x 512 threads, VGPR 104 no-spill) + s_setprio(1) around the QK
// and PV MFMA clusters (T5: pays when co-resident waves are at DIFFERENT
// phases — our 8 waves run the chunk loop barrier-free and independently).
// TLP/ILP structural family closed: v3 interleave re-serialized by compiler
// (r6), 1024-thr spills at VGPR=64 (r9-r11), split-pair doubles epilogue
// cost (r12: +11µs). This is the best-measured structure, micro-tuned.
// ---------------------------------------------------------------------------
__global__ __launch_bounds__(512, 2) void attn(
    const _Float16* __restrict__ qh, const _Float16* __restrict__ ql,
    const _Float16* __restrict__ kf, const _Float16* __restrict__ vt,
    float* __restrict__ out)
{
    __shared__ __align__(16) char smem_raw[69632];
    _Float16* ps = (_Float16*)smem_raw;
    float*    os = (float*)smem_raw;
    __shared__ float sm[8][2][16], sl[8][2][16];

    const int tid = threadIdx.x, lane = tid & 63, w = tid >> 6;
    const int quad = lane >> 4, l16 = lane & 15;
    const int b = blockIdx.x & 3, pair = blockIdx.x >> 2;   // pair 0..63
    const int q0t[2] = {(127 - pair) * 16, pair * 16};
    const int ntk0 = (q0t[0] + 16 + 63) >> 6;
    const int ntk1 = (q0t[1] + 16 + 63) >> 6;
    const int total = ntk0 + ntk1;                          // == 33

    v8h Qh0[2], Qh1[2], Ql0[2], Ql1[2];
    #pragma unroll
    for (int t = 0; t < 2; ++t) {
        const size_t qrow = ((size_t)b * TT + q0t[t] + l16) * HS;
        Qh0[t] = *(const v8h*)(qh + qrow + quad * 8);
        Qh1[t] = *(const v8h*)(qh + qrow + 32 + quad * 8);
        Ql0[t] = *(const v8h*)(ql + qrow + quad * 8);
        Ql1[t] = *(const v8h*)(ql + qrow + 32 + quad * 8);
    }

    const v8h vones = {(_Float16)1.f, (_Float16)1.f, (_Float16)1.f, (_Float16)1.f,
                       (_Float16)1.f, (_Float16)1.f, (_Float16)1.f, (_Float16)1.f};

    float mr0[4] = {-3e38f, -3e38f, -3e38f, -3e38f};
    float mr1[4] = {-3e38f, -3e38f, -3e38f, -3e38f};
    v4f o0[4], o1[4], l40, l41;
    #pragma unroll
    for (int i = 0; i < 4; ++i) {
        o0[i] = (v4f){0.f, 0.f, 0.f, 0.f};
        o1[i] = (v4f){0.f, 0.f, 0.f, 0.f};
    }
    l40 = (v4f){0.f, 0.f, 0.f, 0.f};
    l41 = (v4f){0.f, 0.f, 0.f, 0.f};

    _Float16* pw = ps + w * (16 * 72);

    auto loadK = [&](int j0, v8h (&Kf)[8]) {
        #pragma unroll
        for (int nt = 0; nt < 4; ++nt) {
            const size_t krow = ((size_t)b * TT + j0 + nt * 16 + l16) * HS;
            Kf[nt * 2]     = *(const v8h*)(kf + krow + quad * 8);
            Kf[nt * 2 + 1] = *(const v8h*)(kf + krow + 32 + quad * 8);
        }
    };

    auto doChunk = [&](int j0, int q0c, int t, const v8h (&Kf)[8],
                       float (&mrow)[4], v4f (&o)[4], v4f &o4) {
        v8h Vf[8];
        #pragma unroll
        for (int nt = 0; nt < 4; ++nt) {
            const size_t vrow = ((size_t)(b * HS + nt * 16 + l16)) * TT + j0;
            Vf[nt * 2]     = *(const v8h*)(vt + vrow + quad * 8);
            Vf[nt * 2 + 1] = *(const v8h*)(vt + vrow + 32 + quad * 8);
        }
        v4f s[4];
        #pragma unroll
        for (int i = 0; i < 4; ++i) s[i] = (v4f){0.f, 0.f, 0.f, 0.f};
        __builtin_amdgcn_s_setprio(1);
        #pragma unroll
        for (int nt = 0; nt < 4; ++nt) {
            s[nt] = MFMA_F16(Qh0[t], Kf[nt * 2],     s[nt]);
            s[nt] = MFMA_F16(Qh1[t], Kf[nt * 2 + 1], s[nt]);
            s[nt] = MFMA_F16(Ql0[t], Kf[nt * 2],     s[nt]);
            s[nt] = MFMA_F16(Ql1[t], Kf[nt * 2 + 1], s[nt]);
        }
        __builtin_amdgcn_s_setprio(0);
        const int irow = q0c + quad * 4;
        float mx[4] = {-3e38f, -3e38f, -3e38f, -3e38f};
        #pragma unroll
        for (int nt = 0; nt < 4; ++nt)
            #pragma unroll
            for (int reg = 0; reg < 4; ++reg) {
                if (j0 + nt * 16 + l16 > irow + reg) s[nt][reg] = -3e38f;
                mx[reg] = fmaxf(mx[reg], s[nt][reg]);
            }
        #pragma unroll
        for (int off = 8; off; off >>= 1)
            #pragma unroll
            for (int reg = 0; reg < 4; ++reg)
                mx[reg] = fmaxf(mx[reg], __shfl_xor(mx[reg], off));
        float al[4];
        #pragma unroll
        for (int reg = 0; reg < 4; ++reg) {
            const float mn = fmaxf(mrow[reg], mx[reg]);
            al[reg] = exp2f(mrow[reg] - mn);
            mrow[reg] = mn;
        }
        #pragma unroll
        for (int nt = 0; nt < 4; ++nt)
            #pragma unroll
            for (int reg = 0; reg < 4; ++reg) {
                const float p = (j0 + nt * 16 + l16 > irow + reg)
                                    ? 0.f : exp2f(s[nt][reg] - mrow[reg]);
                pw[(quad * 4 + reg) * 72 + nt * 16 + l16] = (_Float16)p;
            }
        #pragma unroll
        for (int nt = 0; nt < 4; ++nt)
            #pragma unroll
            for (int reg = 0; reg < 4; ++reg)
                o[nt][reg] *= al[reg];
        #pragma unroll
        for (int reg = 0; reg < 4; ++reg)
            o4[reg] *= al[reg];
        const v8h Pa0 = *(const v8h*)(pw + l16 * 72 + quad * 8);
        const v8h Pa1 = *(const v8h*)(pw + l16 * 72 + 32 + quad * 8);
        __builtin_amdgcn_s_setprio(1);
        #pragma unroll
        for (int nt = 0; nt < 4; ++nt) {
            o[nt] = MFMA_F16(Pa0, Vf[nt * 2],     o[nt]);
            o[nt] = MFMA_F16(Pa1, Vf[nt * 2 + 1], o[nt]);
        }
        o4 = MFMA_F16(Pa0, vones, o4);
        o4 = MFMA_F16(Pa1, vones, o4);
        __builtin_amdgcn_s_setprio(0);
    };

    auto jof = [&](int c) { return (c < ntk0) ? c * 64 : (c - ntk0) * 64; };

    // K register double-buffer: issue next chunk's K loads before current
    // chunk's compute (unroll-by-2 keeps KA/KB statically indexed).
    {
        v8h KA[8], KB[8];
        int c = w;                          // w < 8 <= total, always valid
        loadK(jof(c), KA);
        while (true) {
            int cn = c + 8;
            if (cn < total) loadK(jof(cn), KB);
            if (c < ntk0) doChunk(c * 64,          q0t[0], 0, KA, mr0, o0, l40);
            else          doChunk((c - ntk0) * 64, q0t[1], 1, KA, mr1, o1, l41);
            if (cn >= total) break;
            c = cn; cn = c + 8;
            if (cn < total) loadK(jof(cn), KA);
            if (c < ntk0) doChunk(c * 64,          q0t[0], 0, KB, mr0, o0, l40);
            else          doChunk((c - ntk0) * 64, q0t[1], 1, KB, mr1, o1, l41);
            if (cn >= total) break;
            c = cn;
        }
    }

    if (l16 == 0) {
        #pragma unroll
        for (int reg = 0; reg < 4; ++reg) {
            sm[w][0][quad * 4 + reg] = mr0[reg];
            sl[w][0][quad * 4 + reg] = l40[reg];
            sm[w][1][quad * 4 + reg] = mr1[reg];
            sl[w][1][quad * 4 + reg] = l41[reg];
        }
    }
    __syncthreads();

    #pragma unroll
    for (int t = 0; t < 2; ++t) {
        float sc[4];
        #pragma unroll
        for (int reg = 0; reg < 4; ++reg) {
            const int r = quad * 4 + reg;
            float M = sm[0][t][r];
            #pragma unroll
            for (int i = 1; i < 8; ++i) M = fmaxf(M, sm[i][t][r]);
            const float mw = t ? mr1[reg] : mr0[reg];
            sc[reg] = exp2f(mw - M);
        }
        float* ow = os + (size_t)(w * 2 + t) * (16 * 68);
        #pragma unroll
        for (int nt = 0; nt < 4; ++nt)
            #pragma unroll
            for (int reg = 0; reg < 4; ++reg) {
                const v4f& oo = t ? o1[nt] : o0[nt];
                ow[(quad * 4 + reg) * 68 + nt * 16 + l16] = oo[reg] * sc[reg];
            }
    }
    __syncthreads();

    #pragma unroll
    for (int kk = 0; kk < 4; ++kk) {
        const int g = w * 4 + kk;
        const int t = g >> 4, m = g & 15;
        float M = sm[0][t][m];
        #pragma unroll
        for (int i = 1; i < 8; ++i) M = fmaxf(M, sm[i][t][m]);
        float L = 0.f, val = 0.f;
        #pragma unroll
        for (int i = 0; i < 8; ++i) {
            L   += sl[i][t][m] * exp2f(sm[i][t][m] - M);
            val += os[(size_t)(i * 2 + t) * (16 * 68) + m * 68 + lane];
        }
        out[((size_t)b * TT + q0t[t] + m) * HS + lane] = val / L;
    }
}

// ---------------------------------------------------------------------------
extern "C" void kernel_launch(void* const* d_in, const int* in_sizes, int n_in,
                              void* d_out, int out_size, void* d_ws, size_t ws_size,
                              hipStream_t stream)
{
    const float* x  = (const float*)d_in[0];
    const float* Wq = (const float*)d_in[1];
    const float* bq = (const float*)d_in[2];
    const float* Wk = (const float*)d_in[3];
    const float* bk = (const float*)d_in[4];
    const float* Wv = (const float*)d_in[5];
    const float* bv = (const float*)d_in[6];
    float* out = (float*)d_out;

    const int rows = in_sizes[0] / NE;   // 8192
    char* p = (char*)d_ws;
    char* imgW = p;                           p += (size_t)32 * 24576;      // 768 KB
    _Float16* qhb = (_Float16*)p;             p += (size_t)rows * HS * 2;
    _Float16* qlb = (_Float16*)p;             p += (size_t)rows * HS * 2;
    _Float16* kfb = (_Float16*)p;             p += (size_t)rows * HS * 2;
    _Float16* vtb = (_Float16*)p;             p += (size_t)rows * HS * 2;

    prep_w<<<dim3(16, 3), 256, 0, stream>>>(Wq, Wk, Wv, imgW);
    proj<<<rows / 16, 256, 0, stream>>>(x, imgW, bq, bk, bv,
                                        qhb, qlb, kfb, vtb);
    attn<<<rows / 32, 512, 0, stream>>>(qhb, qlb, kfb, vtb, out);
}

// Round 14
// 122.092 us; speedup vs baseline: 1.2636x; 1.0539x over previous
//
#include <hip/hip_runtime.h>
#include <math.h>

// B=4, T=2048, N_EMBD=1024, HEAD=64.
// Reference multiplies scores by sqrt(64)=8; we fold 8*log2(e) into q and use exp2.
#define NE 1024
#define HS 64
#define TT 2048
#define QSC 11.541560327111707f   // 8 * log2(e)

typedef __bf16    v8bf __attribute__((ext_vector_type(8)));
typedef _Float16  v8h  __attribute__((ext_vector_type(8)));
typedef float     v4f  __attribute__((ext_vector_type(4)));

#define MFMA_BF(a, b, c)  __builtin_amdgcn_mfma_f32_16x16x32_bf16((a), (b), (c), 0, 0, 0)
#define MFMA_F16(a, b, c) __builtin_amdgcn_mfma_f32_16x16x32_f16((a), (b), (c), 0, 0, 0)

// async global->LDS DMA (lands at wave-uniform base + lane*size)
__device__ __forceinline__ void gl_lds16(const void* g, void* l) {
    __builtin_amdgcn_global_load_lds(
        (const __attribute__((address_space(1))) unsigned int*)g,
        (__attribute__((address_space(3))) unsigned int*)l, 16, 0, 0);
}

// raw barrier with manual vmcnt: NO compiler-inserted vmcnt(0) drain.
#define SYNC_VM(imm) do {                                   \
    __asm__ __volatile__("" ::: "memory");                  \
    __builtin_amdgcn_s_waitcnt(imm);                        \
    __builtin_amdgcn_s_barrier();                           \
    __asm__ __volatile__("" ::: "memory");                  \
} while (0)
#define WAIT_VM4  0x0F74   // vmcnt(4)
#define WAIT_VM0  0x0F70   // vmcnt(0)

// ---------------------------------------------------------------------------
// prep_w: unchanged.
// ---------------------------------------------------------------------------
__global__ __launch_bounds__(256) void prep_w(
    const float* __restrict__ Wq, const float* __restrict__ Wk,
    const float* __restrict__ Wv, char* __restrict__ imgW)
{
    __shared__ float t[64][65];
    const int bx = blockIdx.x, by = blockIdx.y;
    const float* W = (by == 0) ? Wq : ((by == 1) ? Wk : Wv);
    const int tid = threadIdx.x;
    const int cc = tid & 63, r4 = tid >> 6;
    #pragma unroll
    for (int p = 0; p < 16; ++p) {
        const int k = p * 4 + r4;
        t[k][cc] = W[(size_t)(bx * 64 + k) * HS + cc];   // coalesced
    }
    __syncthreads();
    #pragma unroll
    for (int e = 0; e < 4; ++e) {
        const int chunk = tid + e * 256;
        const int s2   = chunk >> 9;
        const int rem  = chunk & 511;
        const int ctl  = rem >> 7;
        const int rem2 = rem & 127;
        const int pl   = rem2 >> 6;
        const int rem3 = rem2 & 63;
        const int c    = rem3 >> 2;
        const int p16  = rem3 & 3;
        const int kb   = s2 * 32 + ((p16 ^ (c & 3)) << 3);
        const int ncol = ctl * 16 + c;
        v8bf o;
        #pragma unroll
        for (int j = 0; j < 8; ++j) {
            const float v = t[kb + j][ncol];
            const __bf16 h = (__bf16)v;
            o[j] = pl ? (__bf16)(v - (float)h) : h;
        }
        *(v8bf*)(imgW + (size_t)(bx * 2 + s2) * 24576
                 + (by * 4 + ctl) * 2048 + pl * 1024 + c * 64 + p16 * 16) = o;
    }
}

// ---------------------------------------------------------------------------
// Projection GEMM v3: identical main loop to r3-best; epilogue now writes K
// and V in MFMA-FRAGMENT-PACKED order so attn's loads coalesce:
//  kp: per (b, row-group g=t/16): 2KB = [h<32: quad][l16=t%16][8h] | [h>=32 ...]
//  vp: per (b, chunk cj=t/64, hgrp hg=h/16): 2KB = [t'<32: q=t'/8][hr=h%16][8t]
//      | [t'>=32 ...]
// attn reads each fragment as base + lane*16B: one contiguous 1KB per wave.
// Same store count and arithmetic as before (scalar f16 stores, new addresses).
// ---------------------------------------------------------------------------
__global__ __launch_bounds__(256, 2) void proj(
    const float* __restrict__ x, const char* __restrict__ imgW,
    const float* __restrict__ bq, const float* __restrict__ bk,
    const float* __restrict__ bv,
    _Float16* __restrict__ qh, _Float16* __restrict__ ql,
    _Float16* __restrict__ kp, _Float16* __restrict__ vp)
{
    __shared__ __align__(16) char sbuf[3][16384];   // [buf][x 4KB | W 12KB]

    const int tid = threadIdx.x, lane = tid & 63, cg = tid >> 6;
    const int quad = lane >> 4, l16 = lane & 15;
    const int bx = blockIdx.x;
    const int m0 = (bx >> 1) * 32;          // 32-row tile
    const int h  = bx & 1;                  // col half

    const int xrow = cg * 8 + (lane >> 3);
    const int xp   = (lane >> 1) & 3;
    const int xh   = lane & 1;
    const float* gx = x + (size_t)(m0 + xrow) * NE
                        + ((xp ^ (xrow & 3)) << 3) + (xh << 2);
    const int xl = cg * 1024 + lane * 16;
    const char* gw = imgW + (size_t)h * 12288 + (size_t)tid * 16;

    v4f acc[3];
    #pragma unroll
    for (int i = 0; i < 3; ++i) acc[i] = (v4f){0.f, 0.f, 0.f, 0.f};

    #define STAGE(ks, xb_)  do {                                          \
        gl_lds16(gx + (ks) * 32, (xb_) + xl);                             \
        const char* gws_ = gw + (size_t)(ks) * 24576;                     \
        _Pragma("unroll")                                                 \
        for (int j_ = 0; j_ < 3; ++j_)                                    \
            gl_lds16(gws_ + j_ * 4096, (xb_) + 4096 + tid * 16 + j_ * 4096); \
    } while (0)

    auto compute = [&](int ks) {
        const char* xb = sbuf[ks % 3];
        const char* wb = xb + 4096;
        const int mt = cg >> 1;
        const int wc = cg & 1;
        const int rl = mt * 16 + l16;
        const int pA = quad ^ (rl & 3);
        const float4 a0 = *(const float4*)(xb + rl * 128 + pA * 32);
        const float4 a1 = *(const float4*)(xb + rl * 128 + pA * 32 + 16);
        const float av[8] = {a0.x, a0.y, a0.z, a0.w, a1.x, a1.y, a1.z, a1.w};
        v8bf ah, al;
        #pragma unroll
        for (int i = 0; i < 8; ++i) {
            const __bf16 hv = (__bf16)av[i];
            ah[i] = hv;
            al[i] = (__bf16)(av[i] - (float)hv);
        }
        const int wo = l16 * 64 + ((quad ^ (l16 & 3)) << 4);
        #pragma unroll
        for (int j = 0; j < 3; ++j) {
            const char* base = wb + (wc * 3 + j) * 2048 + wo;
            const v8bf bh = *(const v8bf*)(base);
            const v8bf bl = *(const v8bf*)(base + 1024);
            acc[j] = MFMA_BF(ah, bh, acc[j]);
            acc[j] = MFMA_BF(ah, bl, acc[j]);
            acc[j] = MFMA_BF(al, bh, acc[j]);
        }
    };

    STAGE(0, sbuf[0]);
    STAGE(1, sbuf[1]);
    for (int ks = 0; ks < 31; ++ks) {
        SYNC_VM(WAIT_VM4);
        if (ks + 2 < 32) STAGE(ks + 2, sbuf[(ks + 2) % 3]);
        compute(ks);
    }
    SYNC_VM(WAIT_VM0);
    compute(31);
    #undef STAGE

    const int mt = cg >> 1, wc = cg & 1;
    #pragma unroll
    for (int j = 0; j < 3; ++j) {
        const int n = h * 96 + wc * 48 + j * 16 + l16;
        const float bias = (n < 64) ? bq[n] : ((n < 128) ? bk[n - 64] : bv[n - 128]);
        #pragma unroll
        for (int reg = 0; reg < 4; ++reg) {
            const int row = m0 + mt * 16 + quad * 4 + reg;
            const float v = acc[j][reg] + bias;
            if (n < 64) {
                const float s = v * QSC;
                const _Float16 hh = (_Float16)s;
                qh[(size_t)row * HS + n] = hh;
                ql[(size_t)row * HS + n] = (_Float16)(s - (float)hh);
            } else if (n < 128) {
                const int b2 = row >> 11, t = row & 2047, hc = n - 64;
                const size_t base = ((size_t)(b2 * 128) + (t >> 4)) * 1024;
                const int off = (hc < 32)
                    ? (hc >> 3) * 128 + (t & 15) * 8 + (hc & 7)
                    : 512 + ((hc - 32) >> 3) * 128 + (t & 15) * 8 + (hc & 7);
                kp[base + off] = (_Float16)v;
            } else {
                const int b2 = row >> 11, t = row & 2047, hc = n - 128;
                const int cj = t >> 6, tp = t & 63, hg = hc >> 4, hr = hc & 15;
                const size_t base = (((size_t)(b2 * 32) + cj) * 4 + hg) * 1024;
                const int off = (tp < 32)
                    ? (tp >> 3) * 128 + hr * 8 + (tp & 7)
                    : 512 + ((tp - 32) >> 3) * 128 + hr * 8 + (tp & 7);
                vp[base + off] = (_Float16)v;
            }
        }
    }
}

// ---------------------------------------------------------------------------
// Flash attention v9 = r3-best structure (v2 body + K register double-buffer,
// 256 blocks x 512 threads, VGPR ~104 no-spill, no setprio) with COALESCED
// fragment loads: K/V are fragment-packed by proj, so each v8h load is
// base + lane*16B — one contiguous 1KB wave transaction instead of a 64-way
// 128B/4KB-stride scatter. Attacks the measured latency-bound signature
// (MfmaUtil 2.6%, VALUBusy 13-21%, HBM 2%) at its mechanism.
// ---------------------------------------------------------------------------
__global__ __launch_bounds__(512, 2) void attn(
    const _Float16* __restrict__ qh, const _Float16* __restrict__ ql,
    const _Float16* __restrict__ kp, const _Float16* __restrict__ vp,
    float* __restrict__ out)
{
    __shared__ __align__(16) char smem_raw[69632];
    _Float16* ps = (_Float16*)smem_raw;
    float*    os = (float*)smem_raw;
    __shared__ float sm[8][2][16], sl[8][2][16];

    const int tid = threadIdx.x, lane = tid & 63, w = tid >> 6;
    const int quad = lane >> 4, l16 = lane & 15;
    const int b = blockIdx.x & 3, pair = blockIdx.x >> 2;   // pair 0..63
    const int q0t[2] = {(127 - pair) * 16, pair * 16};
    const int ntk0 = (q0t[0] + 16 + 63) >> 6;
    const int ntk1 = (q0t[1] + 16 + 63) >> 6;
    const int total = ntk0 + ntk1;                          // == 33

    v8h Qh0[2], Qh1[2], Ql0[2], Ql1[2];
    #pragma unroll
    for (int t = 0; t < 2; ++t) {
        const size_t qrow = ((size_t)b * TT + q0t[t] + l16) * HS;
        Qh0[t] = *(const v8h*)(qh + qrow + quad * 8);
        Qh1[t] = *(const v8h*)(qh + qrow + 32 + quad * 8);
        Ql0[t] = *(const v8h*)(ql + qrow + quad * 8);
        Ql1[t] = *(const v8h*)(ql + qrow + 32 + quad * 8);
    }

    const v8h vones = {(_Float16)1.f, (_Float16)1.f, (_Float16)1.f, (_Float16)1.f,
                       (_Float16)1.f, (_Float16)1.f, (_Float16)1.f, (_Float16)1.f};

    float mr0[4] = {-3e38f, -3e38f, -3e38f, -3e38f};
    float mr1[4] = {-3e38f, -3e38f, -3e38f, -3e38f};
    v4f o0[4], o1[4], l40, l41;
    #pragma unroll
    for (int i = 0; i < 4; ++i) {
        o0[i] = (v4f){0.f, 0.f, 0.f, 0.f};
        o1[i] = (v4f){0.f, 0.f, 0.f, 0.f};
    }
    l40 = (v4f){0.f, 0.f, 0.f, 0.f};
    l41 = (v4f){0.f, 0.f, 0.f, 0.f};

    _Float16* pw = ps + w * (16 * 72);

    // coalesced: lane*8 halves = lane*16B within a 2KB fragment-packed group
    auto loadK = [&](int j0, v8h (&Kf)[8]) {
        #pragma unroll
        for (int nt = 0; nt < 4; ++nt) {
            const _Float16* kb = kp + ((size_t)(b * 128) + (j0 >> 4) + nt) * 1024
                                    + lane * 8;
            Kf[nt * 2]     = *(const v8h*)(kb);
            Kf[nt * 2 + 1] = *(const v8h*)(kb + 512);
        }
    };

    auto doChunk = [&](int j0, int q0c, int t, const v8h (&Kf)[8],
                       float (&mrow)[4], v4f (&o)[4], v4f &o4) {
        v8h Vf[8];
        #pragma unroll
        for (int nt = 0; nt < 4; ++nt) {
            const _Float16* vb = vp + (((size_t)(b * 32) + (j0 >> 6)) * 4 + nt) * 1024
                                    + lane * 8;
            Vf[nt * 2]     = *(const v8h*)(vb);
            Vf[nt * 2 + 1] = *(const v8h*)(vb + 512);
        }
        v4f s[4];
        #pragma unroll
        for (int i = 0; i < 4; ++i) s[i] = (v4f){0.f, 0.f, 0.f, 0.f};
        #pragma unroll
        for (int nt = 0; nt < 4; ++nt) {
            s[nt] = MFMA_F16(Qh0[t], Kf[nt * 2],     s[nt]);
            s[nt] = MFMA_F16(Qh1[t], Kf[nt * 2 + 1], s[nt]);
            s[nt] = MFMA_F16(Ql0[t], Kf[nt * 2],     s[nt]);
            s[nt] = MFMA_F16(Ql1[t], Kf[nt * 2 + 1], s[nt]);
        }
        const int irow = q0c + quad * 4;
        float mx[4] = {-3e38f, -3e38f, -3e38f, -3e38f};
        #pragma unroll
        for (int nt = 0; nt < 4; ++nt)
            #pragma unroll
            for (int reg = 0; reg < 4; ++reg) {
                if (j0 + nt * 16 + l16 > irow + reg) s[nt][reg] = -3e38f;
                mx[reg] = fmaxf(mx[reg], s[nt][reg]);
            }
        #pragma unroll
        for (int off = 8; off; off >>= 1)
            #pragma unroll
            for (int reg = 0; reg < 4; ++reg)
                mx[reg] = fmaxf(mx[reg], __shfl_xor(mx[reg], off));
        float al[4];
        #pragma unroll
        for (int reg = 0; reg < 4; ++reg) {
            const float mn = fmaxf(mrow[reg], mx[reg]);
            al[reg] = exp2f(mrow[reg] - mn);
            mrow[reg] = mn;
        }
        #pragma unroll
        for (int nt = 0; nt < 4; ++nt)
            #pragma unroll
            for (int reg = 0; reg < 4; ++reg) {
                const float p = (j0 + nt * 16 + l16 > irow + reg)
                                    ? 0.f : exp2f(s[nt][reg] - mrow[reg]);
                pw[(quad * 4 + reg) * 72 + nt * 16 + l16] = (_Float16)p;
            }
        #pragma unroll
        for (int nt = 0; nt < 4; ++nt)
            #pragma unroll
            for (int reg = 0; reg < 4; ++reg)
                o[nt][reg] *= al[reg];
        #pragma unroll
        for (int reg = 0; reg < 4; ++reg)
            o4[reg] *= al[reg];
        const v8h Pa0 = *(const v8h*)(pw + l16 * 72 + quad * 8);
        const v8h Pa1 = *(const v8h*)(pw + l16 * 72 + 32 + quad * 8);
        #pragma unroll
        for (int nt = 0; nt < 4; ++nt) {
            o[nt] = MFMA_F16(Pa0, Vf[nt * 2],     o[nt]);
            o[nt] = MFMA_F16(Pa1, Vf[nt * 2 + 1], o[nt]);
        }
        o4 = MFMA_F16(Pa0, vones, o4);
        o4 = MFMA_F16(Pa1, vones, o4);
    };

    auto jof = [&](int c) { return (c < ntk0) ? c * 64 : (c - ntk0) * 64; };

    // K register double-buffer: issue next chunk's K loads before current
    // chunk's compute (unroll-by-2 keeps KA/KB statically indexed).
    {
        v8h KA[8], KB[8];
        int c = w;                          // w < 8 <= total, always valid
        loadK(jof(c), KA);
        while (true) {
            int cn = c + 8;
            if (cn < total) loadK(jof(cn), KB);
            if (c < ntk0) doChunk(c * 64,          q0t[0], 0, KA, mr0, o0, l40);
            else          doChunk((c - ntk0) * 64, q0t[1], 1, KA, mr1, o1, l41);
            if (cn >= total) break;
            c = cn; cn = c + 8;
            if (cn < total) loadK(jof(cn), KA);
            if (c < ntk0) doChunk(c * 64,          q0t[0], 0, KB, mr0, o0, l40);
            else          doChunk((c - ntk0) * 64, q0t[1], 1, KB, mr1, o1, l41);
            if (cn >= total) break;
            c = cn;
        }
    }

    if (l16 == 0) {
        #pragma unroll
        for (int reg = 0; reg < 4; ++reg) {
            sm[w][0][quad * 4 + reg] = mr0[reg];
            sl[w][0][quad * 4 + reg] = l40[reg];
            sm[w][1][quad * 4 + reg] = mr1[reg];
            sl[w][1][quad * 4 + reg] = l41[reg];
        }
    }
    __syncthreads();

    #pragma unroll
    for (int t = 0; t < 2; ++t) {
        float sc[4];
        #pragma unroll
        for (int reg = 0; reg < 4; ++reg) {
            const int r = quad * 4 + reg;
            float M = sm[0][t][r];
            #pragma unroll
            for (int i = 1; i < 8; ++i) M = fmaxf(M, sm[i][t][r]);
            const float mw = t ? mr1[reg] : mr0[reg];
            sc[reg] = exp2f(mw - M);
        }
        float* ow = os + (size_t)(w * 2 + t) * (16 * 68);
        #pragma unroll
        for (int nt = 0; nt < 4; ++nt)
            #pragma unroll
            for (int reg = 0; reg < 4; ++reg) {
                const v4f& oo = t ? o1[nt] : o0[nt];
                ow[(quad * 4 + reg) * 68 + nt * 16 + l16] = oo[reg] * sc[reg];
            }
    }
    __syncthreads();

    #pragma unroll
    for (int kk = 0; kk < 4; ++kk) {
        const int g = w * 4 + kk;
        const int t = g >> 4, m = g & 15;
        float M = sm[0][t][m];
        #pragma unroll
        for (int i = 1; i < 8; ++i) M = fmaxf(M, sm[i][t][m]);
        float L = 0.f, val = 0.f;
        #pragma unroll
        for (int i = 0; i < 8; ++i) {
            L   += sl[i][t][m] * exp2f(sm[i][t][m] - M);
            val += os[(size_t)(i * 2 + t) * (16 * 68) + m * 68 + lane];
        }
        out[((size_t)b * TT + q0t[t] + m) * HS + lane] = val / L;
    }
}

// ---------------------------------------------------------------------------
extern "C" void kernel_launch(void* const* d_in, const int* in_sizes, int n_in,
                              void* d_out, int out_size, void* d_ws, size_t ws_size,
                              hipStream_t stream)
{
    const float* x  = (const float*)d_in[0];
    const float* Wq = (const float*)d_in[1];
    const float* bq = (const float*)d_in[2];
    const float* Wk = (const float*)d_in[3];
    const float* bk = (const float*)d_in[4];
    const float* Wv = (const float*)d_in[5];
    const float* bv = (const float*)d_in[6];
    float* out = (float*)d_out;

    const int rows = in_sizes[0] / NE;   // 8192
    char* p = (char*)d_ws;
    char* imgW = p;                           p += (size_t)32 * 24576;      // 768 KB
    _Float16* qhb = (_Float16*)p;             p += (size_t)rows * HS * 2;
    _Float16* qlb = (_Float16*)p;             p += (size_t)rows * HS * 2;
    _Float16* kpb = (_Float16*)p;             p += (size_t)rows * HS * 2;   // fragment-packed K
    _Float16* vpb = (_Float16*)p;             p += (size_t)rows * HS * 2;   // fragment-packed V

    prep_w<<<dim3(16, 3), 256, 0, stream>>>(Wq, Wk, Wv, imgW);
    proj<<<rows / 16, 256, 0, stream>>>(x, imgW, bq, bk, bv,
                                        qhb, qlb, kpb, vpb);
    attn<<<rows / 32, 512, 0, stream>>>(qhb, qlb, kpb, vpb, out);
}

// Round 16
// 121.484 us; speedup vs baseline: 1.2699x; 1.0050x over previous
//
#include <hip/hip_runtime.h>
#include <math.h>

// B=4, T=2048, N_EMBD=1024, HEAD=64.
// Reference multiplies scores by sqrt(64)=8; we fold 8*log2(e) into q and use exp2.
#define NE 1024
#define HS 64
#define TT 2048
#define QSC 11.541560327111707f   // 8 * log2(e)

typedef __bf16    v8bf __attribute__((ext_vector_type(8)));
typedef _Float16  v8h  __attribute__((ext_vector_type(8)));
typedef float     v4f  __attribute__((ext_vector_type(4)));

#define MFMA_BF(a, b, c)  __builtin_amdgcn_mfma_f32_16x16x32_bf16((a), (b), (c), 0, 0, 0)
#define MFMA_F16(a, b, c) __builtin_amdgcn_mfma_f32_16x16x32_f16((a), (b), (c), 0, 0, 0)

// async global->LDS DMA (lands at wave-uniform base + lane*size)
__device__ __forceinline__ void gl_lds16(const void* g, void* l) {
    __builtin_amdgcn_global_load_lds(
        (const __attribute__((address_space(1))) unsigned int*)g,
        (__attribute__((address_space(3))) unsigned int*)l, 16, 0, 0);
}

// raw barrier with manual vmcnt: NO compiler-inserted vmcnt(0) drain.
#define SYNC_VM(imm) do {                                   \
    __asm__ __volatile__("" ::: "memory");                  \
    __builtin_amdgcn_s_waitcnt(imm);                        \
    __builtin_amdgcn_s_barrier();                           \
    __asm__ __volatile__("" ::: "memory");                  \
} while (0)
#define WAIT_VM4  0x0F74   // vmcnt(4)
#define WAIT_VM0  0x0F70   // vmcnt(0)

// ---------------------------------------------------------------------------
// prep_w: unchanged.
// ---------------------------------------------------------------------------
__global__ __launch_bounds__(256) void prep_w(
    const float* __restrict__ Wq, const float* __restrict__ Wk,
    const float* __restrict__ Wv, char* __restrict__ imgW)
{
    __shared__ float t[64][65];
    const int bx = blockIdx.x, by = blockIdx.y;
    const float* W = (by == 0) ? Wq : ((by == 1) ? Wk : Wv);
    const int tid = threadIdx.x;
    const int cc = tid & 63, r4 = tid >> 6;
    #pragma unroll
    for (int p = 0; p < 16; ++p) {
        const int k = p * 4 + r4;
        t[k][cc] = W[(size_t)(bx * 64 + k) * HS + cc];   // coalesced
    }
    __syncthreads();
    #pragma unroll
    for (int e = 0; e < 4; ++e) {
        const int chunk = tid + e * 256;
        const int s2   = chunk >> 9;
        const int rem  = chunk & 511;
        const int ctl  = rem >> 7;
        const int rem2 = rem & 127;
        const int pl   = rem2 >> 6;
        const int rem3 = rem2 & 63;
        const int c    = rem3 >> 2;
        const int p16  = rem3 & 3;
        const int kb   = s2 * 32 + ((p16 ^ (c & 3)) << 3);
        const int ncol = ctl * 16 + c;
        v8bf o;
        #pragma unroll
        for (int j = 0; j < 8; ++j) {
            const float v = t[kb + j][ncol];
            const __bf16 h = (__bf16)v;
            o[j] = pl ? (__bf16)(v - (float)h) : h;
        }
        *(v8bf*)(imgW + (size_t)(bx * 2 + s2) * 24576
                 + (by * 4 + ctl) * 2048 + pl * 1024 + c * 64 + p16 * 16) = o;
    }
}

// ---------------------------------------------------------------------------
// Projection GEMM v3 (unchanged from r14): fragment-packed K/V epilogue.
// ---------------------------------------------------------------------------
__global__ __launch_bounds__(256, 2) void proj(
    const float* __restrict__ x, const char* __restrict__ imgW,
    const float* __restrict__ bq, const float* __restrict__ bk,
    const float* __restrict__ bv,
    _Float16* __restrict__ qh, _Float16* __restrict__ ql,
    _Float16* __restrict__ kp, _Float16* __restrict__ vp)
{
    __shared__ __align__(16) char sbuf[3][16384];   // [buf][x 4KB | W 12KB]

    const int tid = threadIdx.x, lane = tid & 63, cg = tid >> 6;
    const int quad = lane >> 4, l16 = lane & 15;
    const int bx = blockIdx.x;
    const int m0 = (bx >> 1) * 32;          // 32-row tile
    const int h  = bx & 1;                  // col half

    const int xrow = cg * 8 + (lane >> 3);
    const int xp   = (lane >> 1) & 3;
    const int xh   = lane & 1;
    const float* gx = x + (size_t)(m0 + xrow) * NE
                        + ((xp ^ (xrow & 3)) << 3) + (xh << 2);
    const int xl = cg * 1024 + lane * 16;
    const char* gw = imgW + (size_t)h * 12288 + (size_t)tid * 16;

    v4f acc[3];
    #pragma unroll
    for (int i = 0; i < 3; ++i) acc[i] = (v4f){0.f, 0.f, 0.f, 0.f};

    #define STAGE(ks, xb_)  do {                                          \
        gl_lds16(gx + (ks) * 32, (xb_) + xl);                             \
        const char* gws_ = gw + (size_t)(ks) * 24576;                     \
        _Pragma("unroll")                                                 \
        for (int j_ = 0; j_ < 3; ++j_)                                    \
            gl_lds16(gws_ + j_ * 4096, (xb_) + 4096 + tid * 16 + j_ * 4096); \
    } while (0)

    auto compute = [&](int ks) {
        const char* xb = sbuf[ks % 3];
        const char* wb = xb + 4096;
        const int mt = cg >> 1;
        const int wc = cg & 1;
        const int rl = mt * 16 + l16;
        const int pA = quad ^ (rl & 3);
        const float4 a0 = *(const float4*)(xb + rl * 128 + pA * 32);
        const float4 a1 = *(const float4*)(xb + rl * 128 + pA * 32 + 16);
        const float av[8] = {a0.x, a0.y, a0.z, a0.w, a1.x, a1.y, a1.z, a1.w};
        v8bf ah, al;
        #pragma unroll
        for (int i = 0; i < 8; ++i) {
            const __bf16 hv = (__bf16)av[i];
            ah[i] = hv;
            al[i] = (__bf16)(av[i] - (float)hv);
        }
        const int wo = l16 * 64 + ((quad ^ (l16 & 3)) << 4);
        #pragma unroll
        for (int j = 0; j < 3; ++j) {
            const char* base = wb + (wc * 3 + j) * 2048 + wo;
            const v8bf bh = *(const v8bf*)(base);
            const v8bf bl = *(const v8bf*)(base + 1024);
            acc[j] = MFMA_BF(ah, bh, acc[j]);
            acc[j] = MFMA_BF(ah, bl, acc[j]);
            acc[j] = MFMA_BF(al, bh, acc[j]);
        }
    };

    STAGE(0, sbuf[0]);
    STAGE(1, sbuf[1]);
    for (int ks = 0; ks < 31; ++ks) {
        SYNC_VM(WAIT_VM4);
        if (ks + 2 < 32) STAGE(ks + 2, sbuf[(ks + 2) % 3]);
        compute(ks);
    }
    SYNC_VM(WAIT_VM0);
    compute(31);
    #undef STAGE

    const int mt = cg >> 1, wc = cg & 1;
    #pragma unroll
    for (int j = 0; j < 3; ++j) {
        const int n = h * 96 + wc * 48 + j * 16 + l16;
        const float bias = (n < 64) ? bq[n] : ((n < 128) ? bk[n - 64] : bv[n - 128]);
        #pragma unroll
        for (int reg = 0; reg < 4; ++reg) {
            const int row = m0 + mt * 16 + quad * 4 + reg;
            const float v = acc[j][reg] + bias;
            if (n < 64) {
                const float s = v * QSC;
                const _Float16 hh = (_Float16)s;
                qh[(size_t)row * HS + n] = hh;
                ql[(size_t)row * HS + n] = (_Float16)(s - (float)hh);
            } else if (n < 128) {
                const int b2 = row >> 11, t = row & 2047, hc = n - 64;
                const size_t base = ((size_t)(b2 * 128) + (t >> 4)) * 1024;
                const int off = (hc < 32)
                    ? (hc >> 3) * 128 + (t & 15) * 8 + (hc & 7)
                    : 512 + ((hc - 32) >> 3) * 128 + (t & 15) * 8 + (hc & 7);
                kp[base + off] = (_Float16)v;
            } else {
                const int b2 = row >> 11, t = row & 2047, hc = n - 128;
                const int cj = t >> 6, tp = t & 63, hg = hc >> 4, hr = hc & 15;
                const size_t base = (((size_t)(b2 * 32) + cj) * 4 + hg) * 1024;
                const int off = (tp < 32)
                    ? (tp >> 3) * 128 + hr * 8 + (tp & 7)
                    : 512 + ((tp - 32) >> 3) * 128 + hr * 8 + (tp & 7);
                vp[base + off] = (_Float16)v;
            }
        }
    }
}

// ---------------------------------------------------------------------------
// Flash attention v10: single-tile blocks, 2 blocks/CU. r14's coalesced
// fragment loads confirmed (−5.7µs, matched prediction). Still latency-bound
// at 1 blk/CU, so double TLP the no-duplication way: one q-tile per block
// (512 blocks = 4 b x 128 tiles), heavy tiles dispatched FIRST (LPT balance:
// tile = 127 - bx>>2, ntk = 1..32 chunks). Each block: half the Q regs, one
// single-tile merge -> same total epilogue work as r14, zero duplication
// (unlike r12's split-pair, +11µs). LDS padded to 56KB so max 2 blocks/CU ->
// compiler VGPR budget 128 >= need (~104); 2x co-residency hides chunk-chain
// latency. Empty waves (w >= ntk) contribute exp2(-3e38-M)=0 exactly.
// ---------------------------------------------------------------------------
__global__ __launch_bounds__(512, 2) void attn(
    const _Float16* __restrict__ qh, const _Float16* __restrict__ ql,
    const _Float16* __restrict__ kp, const _Float16* __restrict__ vp,
    float* __restrict__ out)
{
    __shared__ __align__(16) char smem_raw[57344];   // P 18KB / os 34.8KB time-shared; 56KB caps 2 blk/CU
    _Float16* ps = (_Float16*)smem_raw;
    float*    os = (float*)smem_raw;
    __shared__ float sm[8][16], sl[8][16];

    const int tid = threadIdx.x, lane = tid & 63, w = tid >> 6;
    const int quad = lane >> 4, l16 = lane & 15;
    const int bx = blockIdx.x;
    const int b = bx & 3, tile = 127 - (bx >> 2);   // heavy-first dispatch
    const int q0 = tile * 16;
    const int ntk = (q0 + 16 + 63) >> 6;            // 1..32 chunks

    v8h Qh0, Qh1, Ql0, Ql1;
    {
        const size_t qrow = ((size_t)b * TT + q0 + l16) * HS;
        Qh0 = *(const v8h*)(qh + qrow + quad * 8);
        Qh1 = *(const v8h*)(qh + qrow + 32 + quad * 8);
        Ql0 = *(const v8h*)(ql + qrow + quad * 8);
        Ql1 = *(const v8h*)(ql + qrow + 32 + quad * 8);
    }

    const v8h vones = {(_Float16)1.f, (_Float16)1.f, (_Float16)1.f, (_Float16)1.f,
                       (_Float16)1.f, (_Float16)1.f, (_Float16)1.f, (_Float16)1.f};

    float mr[4] = {-3e38f, -3e38f, -3e38f, -3e38f};
    v4f o[4], l4;
    #pragma unroll
    for (int i = 0; i < 4; ++i) o[i] = (v4f){0.f, 0.f, 0.f, 0.f};
    l4 = (v4f){0.f, 0.f, 0.f, 0.f};

    _Float16* pw = ps + w * (16 * 72);

    // coalesced fragment loads (r14 layout): base + lane*16B
    auto loadK = [&](int j0, v8h (&Kf)[8]) {
        #pragma unroll
        for (int nt = 0; nt < 4; ++nt) {
            const _Float16* kb = kp + ((size_t)(b * 128) + (j0 >> 4) + nt) * 1024
                                    + lane * 8;
            Kf[nt * 2]     = *(const v8h*)(kb);
            Kf[nt * 2 + 1] = *(const v8h*)(kb + 512);
        }
    };

    auto doChunk = [&](int j0, const v8h (&Kf)[8]) {
        v8h Vf[8];
        #pragma unroll
        for (int nt = 0; nt < 4; ++nt) {
            const _Float16* vb = vp + (((size_t)(b * 32) + (j0 >> 6)) * 4 + nt) * 1024
                                    + lane * 8;
            Vf[nt * 2]     = *(const v8h*)(vb);
            Vf[nt * 2 + 1] = *(const v8h*)(vb + 512);
        }
        v4f s[4];
        #pragma unroll
        for (int i = 0; i < 4; ++i) s[i] = (v4f){0.f, 0.f, 0.f, 0.f};
        #pragma unroll
        for (int nt = 0; nt < 4; ++nt) {
            s[nt] = MFMA_F16(Qh0, Kf[nt * 2],     s[nt]);
            s[nt] = MFMA_F16(Qh1, Kf[nt * 2 + 1], s[nt]);
            s[nt] = MFMA_F16(Ql0, Kf[nt * 2],     s[nt]);
            s[nt] = MFMA_F16(Ql1, Kf[nt * 2 + 1], s[nt]);
        }
        const int irow = q0 + quad * 4;
        float mx[4] = {-3e38f, -3e38f, -3e38f, -3e38f};
        #pragma unroll
        for (int nt = 0; nt < 4; ++nt)
            #pragma unroll
            for (int reg = 0; reg < 4; ++reg) {
                if (j0 + nt * 16 + l16 > irow + reg) s[nt][reg] = -3e38f;
                mx[reg] = fmaxf(mx[reg], s[nt][reg]);
            }
        #pragma unroll
        for (int off = 8; off; off >>= 1)
            #pragma unroll
            for (int reg = 0; reg < 4; ++reg)
                mx[reg] = fmaxf(mx[reg], __shfl_xor(mx[reg], off));
        float al[4];
        #pragma unroll
        for (int reg = 0; reg < 4; ++reg) {
            const float mn = fmaxf(mr[reg], mx[reg]);
            al[reg] = exp2f(mr[reg] - mn);
            mr[reg] = mn;
        }
        #pragma unroll
        for (int nt = 0; nt < 4; ++nt)
            #pragma unroll
            for (int reg = 0; reg < 4; ++reg) {
                const float p = (j0 + nt * 16 + l16 > irow + reg)
                                    ? 0.f : exp2f(s[nt][reg] - mr[reg]);
                pw[(quad * 4 + reg) * 72 + nt * 16 + l16] = (_Float16)p;
            }
        #pragma unroll
        for (int nt = 0; nt < 4; ++nt)
            #pragma unroll
            for (int reg = 0; reg < 4; ++reg)
                o[nt][reg] *= al[reg];
        #pragma unroll
        for (int reg = 0; reg < 4; ++reg)
            l4[reg] *= al[reg];
        const v8h Pa0 = *(const v8h*)(pw + l16 * 72 + quad * 8);
        const v8h Pa1 = *(const v8h*)(pw + l16 * 72 + 32 + quad * 8);
        #pragma unroll
        for (int nt = 0; nt < 4; ++nt) {
            o[nt] = MFMA_F16(Pa0, Vf[nt * 2],     o[nt]);
            o[nt] = MFMA_F16(Pa1, Vf[nt * 2 + 1], o[nt]);
        }
        l4 = MFMA_F16(Pa0, vones, l4);
        l4 = MFMA_F16(Pa1, vones, l4);
    };

    // K register double-buffer over this tile's chunks (wave w: c = w, w+8, ...)
    if (w < ntk) {
        v8h KA[8], KB[8];
        int c = w;
        loadK(c * 64, KA);
        while (true) {
            int cn = c + 8;
            if (cn < ntk) loadK(cn * 64, KB);
            doChunk(c * 64, KA);
            if (cn >= ntk) break;
            c = cn; cn = c + 8;
            if (cn < ntk) loadK(cn * 64, KA);
            doChunk(c * 64, KB);
            if (cn >= ntk) break;
            c = cn;
        }
    }

    if (l16 == 0) {
        #pragma unroll
        for (int reg = 0; reg < 4; ++reg) {
            sm[w][quad * 4 + reg] = mr[reg];
            sl[w][quad * 4 + reg] = l4[reg];
        }
    }
    __syncthreads();

    {
        float sc[4];
        #pragma unroll
        for (int reg = 0; reg < 4; ++reg) {
            const int r = quad * 4 + reg;
            float M = sm[0][r];
            #pragma unroll
            for (int i = 1; i < 8; ++i) M = fmaxf(M, sm[i][r]);
            sc[reg] = exp2f(mr[reg] - M);     // 0 for empty waves (mr = -3e38)
        }
        float* ow = os + (size_t)w * (16 * 68);
        #pragma unroll
        for (int nt = 0; nt < 4; ++nt)
            #pragma unroll
            for (int reg = 0; reg < 4; ++reg)
                ow[(quad * 4 + reg) * 68 + nt * 16 + l16] = o[nt][reg] * sc[reg];
    }
    __syncthreads();

    #pragma unroll
    for (int kk = 0; kk < 2; ++kk) {
        const int m = w * 2 + kk;             // 0..15
        float M = sm[0][m];
        #pragma unroll
        for (int i = 1; i < 8; ++i) M = fmaxf(M, sm[i][m]);
        float L = 0.f, val = 0.f;
        #pragma unroll
        for (int i = 0; i < 8; ++i) {
            L   += sl[i][m] * exp2f(sm[i][m] - M);
            val += os[(size_t)i * (16 * 68) + m * 68 + lane];
        }
        out[((size_t)b * TT + q0 + m) * HS + lane] = val / L;
    }
}

// ---------------------------------------------------------------------------
extern "C" void kernel_launch(void* const* d_in, const int* in_sizes, int n_in,
                              void* d_out, int out_size, void* d_ws, size_t ws_size,
                              hipStream_t stream)
{
    const float* x  = (const float*)d_in[0];
    const float* Wq = (const float*)d_in[1];
    const float* bq = (const float*)d_in[2];
    const float* Wk = (const float*)d_in[3];
    const float* bk = (const float*)d_in[4];
    const float* Wv = (const float*)d_in[5];
    const float* bv = (const float*)d_in[6];
    float* out = (float*)d_out;

    const int rows = in_sizes[0] / NE;   // 8192
    char* p = (char*)d_ws;
    char* imgW = p;                           p += (size_t)32 * 24576;      // 768 KB
    _Float16* qhb = (_Float16*)p;             p += (size_t)rows * HS * 2;
    _Float16* qlb = (_Float16*)p;             p += (size_t)rows * HS * 2;
    _Float16* kpb = (_Float16*)p;             p += (size_t)rows * HS * 2;   // fragment-packed K
    _Float16* vpb = (_Float16*)p;             p += (size_t)rows * HS * 2;   // fragment-packed V

    prep_w<<<dim3(16, 3), 256, 0, stream>>>(Wq, Wk, Wv, imgW);
    proj<<<rows / 16, 256, 0, stream>>>(x, imgW, bq, bk, bv,
                                        qhb, qlb, kpb, vpb);
    attn<<<rows / 16, 512, 0, stream>>>(qhb, qlb, kpb, vpb, out);
}